// Round 1
// baseline (1694.708 us; speedup 1.0000x reference)
//
#include <hip/hip_runtime.h>
#include <float.h>

#define N 8192
#define D 512
#define DZ 64
#define KNN 10
#define REGC 1e-6f

#define BI 64
#define BJ 64
#define BK 32
#define NCHUNK 4
#define JCHUNK (N / NCHUNK)  // 2048

// ---------------- kernel 1: row squared norms ----------------
__global__ __launch_bounds__(64) void sqnorm_kernel(const float* __restrict__ X,
                                                    float* __restrict__ sq) {
  const int i = blockIdx.x;
  const int lane = threadIdx.x;
  float s = 0.f;
#pragma unroll
  for (int c = 0; c < D / 64; ++c) {
    float v = X[(size_t)i * D + c * 64 + lane];
    s = fmaf(v, v, s);
  }
#pragma unroll
  for (int off = 32; off; off >>= 1) s += __shfl_xor(s, off);
  if (lane == 0) sq[i] = s;
}

// ---------------- kernel 2: fused distance-GEMM + per-row top-10 ----------------
// grid: (N/BI, NCHUNK), block: 256. Each block: 64 rows x 2048 cols, K=512.
// key(i,j) = sq[j] - 2*dot(X_i,X_j)  (rank-equivalent to D2; sq[i] constant per row)
__global__ __launch_bounds__(256) void knn_kernel(const float* __restrict__ X,
                                                  const float* __restrict__ sq,
                                                  float* __restrict__ knn_val,
                                                  int* __restrict__ knn_idx) {
  __shared__ float As[BI][BK + 4];
  __shared__ float Bs[BJ][BK + 4];
  __shared__ float keys[BI][BJ + 4];
  __shared__ float topv[BI][KNN];
  __shared__ int topi[BI][KNN];

  const int i0 = blockIdx.x * BI;
  const int chunk = blockIdx.y;
  const int jbase = chunk * JCHUNK;
  const int tid = threadIdx.x;
  const int tr = tid >> 4;        // 0..15
  const int tc = tid & 15;        // 0..15
  const int lrow = tid >> 2;      // 0..63   (staging row)
  const int lq = (tid & 3) << 2;  // 0,4,8,12 (staging quad col)

  for (int e = tid; e < BI * KNN; e += 256) {
    topv[e / KNN][e % KNN] = FLT_MAX;
    topi[e / KNN][e % KNN] = -1;
  }

  for (int jt = 0; jt < JCHUNK / BJ; ++jt) {
    const int j0 = jbase + jt * BJ;
    float acc[4][4];
#pragma unroll
    for (int u = 0; u < 4; ++u)
#pragma unroll
      for (int v = 0; v < 4; ++v) acc[u][v] = 0.f;

    for (int kt = 0; kt < D / BK; ++kt) {
      const int k0 = kt * BK;
      const float4 a0 = *(const float4*)&X[(size_t)(i0 + lrow) * D + k0 + lq];
      const float4 a1 = *(const float4*)&X[(size_t)(i0 + lrow) * D + k0 + lq + 16];
      const float4 b0 = *(const float4*)&X[(size_t)(j0 + lrow) * D + k0 + lq];
      const float4 b1 = *(const float4*)&X[(size_t)(j0 + lrow) * D + k0 + lq + 16];
      __syncthreads();  // previous compute (and prior selection / init) done
      *(float4*)&As[lrow][lq] = a0;
      *(float4*)&As[lrow][lq + 16] = a1;
      *(float4*)&Bs[lrow][lq] = b0;
      *(float4*)&Bs[lrow][lq + 16] = b1;
      __syncthreads();
#pragma unroll
      for (int kk = 0; kk < BK; ++kk) {
        float a[4], b[4];
#pragma unroll
        for (int u = 0; u < 4; ++u) a[u] = As[tr + 16 * u][kk];
#pragma unroll
        for (int v = 0; v < 4; ++v) b[v] = Bs[tc + 16 * v][kk];
#pragma unroll
        for (int u = 0; u < 4; ++u)
#pragma unroll
          for (int v = 0; v < 4; ++v) acc[u][v] = fmaf(a[u], b[v], acc[u][v]);
      }
    }

    float sqv[4];
#pragma unroll
    for (int v = 0; v < 4; ++v) sqv[v] = sq[j0 + tc + 16 * v];
#pragma unroll
    for (int u = 0; u < 4; ++u)
#pragma unroll
      for (int v = 0; v < 4; ++v)
        keys[tr + 16 * u][tc + 16 * v] = sqv[v] - 2.f * acc[u][v];
    __syncthreads();

    if (tid < BI) {  // one thread per row: maintain sorted top-10
      const int r = tid;
      const int gi = i0 + r;
      float worst = topv[r][KNN - 1];
      for (int c = 0; c < BJ; ++c) {
        const float v = keys[r][c];
        const int j = j0 + c;
        if (v < worst && j != gi) {
          int p = KNN - 1;
          while (p > 0 && topv[r][p - 1] > v) {
            topv[r][p] = topv[r][p - 1];
            topi[r][p] = topi[r][p - 1];
            --p;
          }
          topv[r][p] = v;
          topi[r][p] = j;
          worst = topv[r][KNN - 1];
        }
      }
    }
    __syncthreads();
  }

  if (tid < BI) {
    const int gi = i0 + tid;
    for (int k = 0; k < KNN; ++k) {
      knn_val[((size_t)gi * NCHUNK + chunk) * KNN + k] = topv[tid][k];
      knn_idx[((size_t)gi * NCHUNK + chunk) * KNN + k] = topi[tid][k];
    }
  }
}

// ---------------- kernel 3: merge chunks, solve 10x10, loss ----------------
__global__ __launch_bounds__(64) void lle_loss_kernel(const float* __restrict__ X,
                                                      const float* __restrict__ Z,
                                                      const float* __restrict__ knn_val,
                                                      const int* __restrict__ knn_idx,
                                                      float* __restrict__ out) {
  const int i = blockIdx.x;
  const int lane = threadIdx.x;
  __shared__ int nbr[KNN];
  __shared__ float Cm[KNN][KNN];
  __shared__ float ysh[KNN];
  __shared__ float wsh[KNN];

  if (lane == 0) {  // merge 4 chunk lists -> global top-10 (index-stable)
    float bv[KNN];
    int bix[KNN];
    for (int k = 0; k < KNN; ++k) { bv[k] = FLT_MAX; bix[k] = -1; }
    for (int c = 0; c < NCHUNK * KNN; ++c) {
      const float v = knn_val[(size_t)i * NCHUNK * KNN + c];
      const int id = knn_idx[(size_t)i * NCHUNK * KNN + c];
      if (v < bv[KNN - 1]) {
        int p = KNN - 1;
        while (p > 0 && bv[p - 1] > v) {
          bv[p] = bv[p - 1];
          bix[p] = bix[p - 1];
          --p;
        }
        bv[p] = v;
        bix[p] = id;
      }
    }
    for (int k = 0; k < KNN; ++k) nbr[k] = bix[k];
  }
  __syncthreads();

  // diffs in registers, statically indexed
  float xi[D / 64], df[KNN][D / 64];
#pragma unroll
  for (int c = 0; c < D / 64; ++c) xi[c] = X[(size_t)i * D + c * 64 + lane];
#pragma unroll
  for (int k = 0; k < KNN; ++k) {
    const int j = nbr[k];
#pragma unroll
    for (int c = 0; c < D / 64; ++c)
      df[k][c] = X[(size_t)j * D + c * 64 + lane] - xi[c];
  }

  // C = diff diff^T via wave reductions
#pragma unroll
  for (int k = 0; k < KNN; ++k) {
#pragma unroll
    for (int l = k; l < KNN; ++l) {
      float p = 0.f;
#pragma unroll
      for (int c = 0; c < D / 64; ++c) p = fmaf(df[k][c], df[l][c], p);
#pragma unroll
      for (int off = 32; off; off >>= 1) p += __shfl_xor(p, off);
      if (lane == 0) {
        Cm[k][l] = p;
        Cm[l][k] = p;
      }
    }
  }

  if (lane == 0) {  // Cholesky solve in LDS (avoids scratch from runtime idx)
    for (int j = 0; j < KNN; ++j) Cm[j][j] += REGC;
    for (int j = 0; j < KNN; ++j) {
      float s = Cm[j][j];
      for (int t = 0; t < j; ++t) s -= Cm[j][t] * Cm[j][t];
      const float Ljj = sqrtf(s);
      Cm[j][j] = Ljj;
      const float inv = 1.f / Ljj;
      for (int r = j + 1; r < KNN; ++r) {
        float s2 = Cm[r][j];
        for (int t = 0; t < j; ++t) s2 -= Cm[r][t] * Cm[j][t];
        Cm[r][j] = s2 * inv;
      }
    }
    for (int r = 0; r < KNN; ++r) {  // L y = 1
      float s = 1.f;
      for (int t = 0; t < r; ++t) s -= Cm[r][t] * ysh[t];
      ysh[r] = s / Cm[r][r];
    }
    for (int r = KNN - 1; r >= 0; --r) {  // L^T w = y
      float s2 = ysh[r];
      for (int t = r + 1; t < KNN; ++t) s2 -= Cm[t][r] * wsh[t];
      wsh[r] = s2 / Cm[r][r];
    }
    float s = 0.f;
    for (int k = 0; k < KNN; ++k) s += wsh[k];
    const float invs = 1.f / s;
    for (int k = 0; k < KNN; ++k) wsh[k] *= invs;
  }
  __syncthreads();

  // lane == output dim (DZ == 64)
  float zr = 0.f;
#pragma unroll
  for (int k = 0; k < KNN; ++k)
    zr = fmaf(wsh[k], Z[(size_t)nbr[k] * DZ + lane], zr);
  const float e = zr - Z[(size_t)i * DZ + lane];
  float se = e * e;
#pragma unroll
  for (int off = 32; off; off >>= 1) se += __shfl_xor(se, off);
  if (lane == 0) atomicAdd(out, se * (1.f / ((float)N * DZ)));
}

// ---------------- launch ----------------
extern "C" void kernel_launch(void* const* d_in, const int* in_sizes, int n_in,
                              void* d_out, int out_size, void* d_ws, size_t ws_size,
                              hipStream_t stream) {
  const float* X = (const float*)d_in[0];
  const float* Z = (const float*)d_in[1];
  float* out = (float*)d_out;

  char* ws = (char*)d_ws;
  float* sq = (float*)ws;                                   // N floats
  float* knn_val = (float*)(ws + (size_t)N * sizeof(float));  // N*NCHUNK*KNN
  int* knn_idx = (int*)(ws + (size_t)N * sizeof(float) +
                        (size_t)N * NCHUNK * KNN * sizeof(float));

  hipMemsetAsync(d_out, 0, sizeof(float), stream);
  sqnorm_kernel<<<N, 64, 0, stream>>>(X, sq);
  knn_kernel<<<dim3(N / BI, NCHUNK), 256, 0, stream>>>(X, sq, knn_val, knn_idx);
  lle_loss_kernel<<<N, 64, 0, stream>>>(X, Z, knn_val, knn_idx, out);
}

// Round 2
// 1203.446 us; speedup vs baseline: 1.4082x; 1.4082x over previous
//
#include <hip/hip_runtime.h>
#include <hip/hip_bf16.h>
#include <float.h>

#define N 8192
#define D 512
#define DZ 64
#define KNN 10
#define KSEL 16
#define REGC 1e-6f

#define BI 128
#define BJ 128
#define BK 32
#define NCHUNK 8
#define JCHUNK (N / NCHUNK)  // 1024
#define NJT (JCHUNK / BJ)    // 8

typedef __attribute__((ext_vector_type(8))) short short8v;  // 8 bf16 (4 VGPR)
typedef __attribute__((ext_vector_type(4))) float f32x4;    // MFMA acc
typedef __attribute__((ext_vector_type(4))) int int4v;      // 16B move

// ---------------- kernel 0: sq (fp32) + bf16 copy of X ----------------
__global__ __launch_bounds__(64) void prep_kernel(const float* __restrict__ X,
                                                  float* __restrict__ sq,
                                                  ushort* __restrict__ Xb) {
  const int i = blockIdx.x;
  const int lane = threadIdx.x;
  const float4 v0 = *(const float4*)&X[(size_t)i * D + lane * 8];
  const float4 v1 = *(const float4*)&X[(size_t)i * D + lane * 8 + 4];
  float vv[8] = {v0.x, v0.y, v0.z, v0.w, v1.x, v1.y, v1.z, v1.w};
  ushort h[8];
  float s = 0.f;
#pragma unroll
  for (int j = 0; j < 8; ++j) {
    s = fmaf(vv[j], vv[j], s);
    __hip_bfloat16 b = __float2bfloat16(vv[j]);
    h[j] = *(ushort*)&b;
  }
  *(int4v*)&Xb[(size_t)i * D + lane * 8] = *(int4v*)h;
#pragma unroll
  for (int off = 32; off; off >>= 1) s += __shfl_xor(s, off);
  if (lane == 0) sq[i] = s;
}

// ---------------- kernel 1: bf16 MFMA distance GEMM + approx top-16 ----------------
// grid (N/BI, NCHUNK), 256 threads = 4 waves (2x2), wave tile 64x64 = 4x4 MFMA frags.
// key(i,j) = sq[j] - 2*dot_bf16(x_i, x_j)  (rank proxy; rescored exactly later)
__global__ __launch_bounds__(256) void knn_kernel(const ushort* __restrict__ Xb,
                                                  const float* __restrict__ sq,
                                                  float* __restrict__ cand_val,
                                                  int* __restrict__ cand_idx) {
  __shared__ ushort As[BI][BK];    // 8 KB
  __shared__ ushort Bs[BJ][BK];    // 8 KB
  __shared__ float keys[BI][65];   // 33.3 KB, stride 65 -> (r+c)%32 banks, 2-way free
  __shared__ float topv[BI][KSEL]; // 8 KB
  __shared__ int topi[BI][KSEL];   // 8 KB

  const int i0 = blockIdx.x * BI;
  const int chunk = blockIdx.y;
  const int tid = threadIdx.x;
  const int lane = tid & 63;
  const int wave = tid >> 6;
  const int wr = wave >> 1;  // wave row 0..1
  const int wc = wave & 1;   // wave col 0..1

  for (int e = tid; e < BI * KSEL; e += 256) {
    topv[e / KSEL][e % KSEL] = FLT_MAX;
    topi[e / KSEL][e % KSEL] = -1;
  }
  __syncthreads();

  const int srow = tid >> 2;        // staging row 0..63
  const int scol = (tid & 3) * 8;   // staging col (bf16 elems), 16B chunks
  const int q = lane >> 4;          // 0..3
  const int cr = lane & 15;         // 0..15

  for (int jt = 0; jt < NJT; ++jt) {
    const int j0 = chunk * JCHUNK + jt * BJ;
    f32x4 acc[4][4];
#pragma unroll
    for (int m = 0; m < 4; ++m)
#pragma unroll
      for (int n = 0; n < 4; ++n) acc[m][n] = (f32x4){0.f, 0.f, 0.f, 0.f};

    for (int kt = 0; kt < D / BK; ++kt) {
      const int k0 = kt * BK;
      // reg-stage 16B per thread per tile-half (issued before barrier)
      const int4v a0 = *(const int4v*)&Xb[(size_t)(i0 + srow) * D + k0 + scol];
      const int4v a1 = *(const int4v*)&Xb[(size_t)(i0 + 64 + srow) * D + k0 + scol];
      const int4v b0 = *(const int4v*)&Xb[(size_t)(j0 + srow) * D + k0 + scol];
      const int4v b1 = *(const int4v*)&Xb[(size_t)(j0 + 64 + srow) * D + k0 + scol];
      __syncthreads();  // previous LDS reads (MFMA frags / keys scan) done
      *(int4v*)&As[srow][scol] = a0;
      *(int4v*)&As[64 + srow][scol] = a1;
      *(int4v*)&Bs[srow][scol] = b0;
      *(int4v*)&Bs[64 + srow][scol] = b1;
      __syncthreads();

      short8v a[4], b[4];
#pragma unroll
      for (int m = 0; m < 4; ++m)
        a[m] = *(const short8v*)&As[wr * 64 + m * 16 + cr][q * 8];
#pragma unroll
      for (int n = 0; n < 4; ++n)
        b[n] = *(const short8v*)&Bs[wc * 64 + n * 16 + cr][q * 8];
#pragma unroll
      for (int m = 0; m < 4; ++m)
#pragma unroll
        for (int n = 0; n < 4; ++n)
          acc[m][n] = __builtin_amdgcn_mfma_f32_16x16x32_bf16(a[m], b[n], acc[m][n], 0, 0, 0);
    }

    // keys + selection in two 64-col halves (halves LDS for keys)
#pragma unroll 1
    for (int h = 0; h < 2; ++h) {
      __syncthreads();  // previous half's scan done before overwrite
      if (wc == h) {
        // C/D layout: col = lane&15, row = (lane>>4)*4 + reg  [m89-verified]
#pragma unroll
        for (int n = 0; n < 4; ++n) {
          const float sqj = sq[j0 + h * 64 + n * 16 + cr];
#pragma unroll
          for (int m = 0; m < 4; ++m) {
#pragma unroll
            for (int s = 0; s < 4; ++s)
              keys[wr * 64 + m * 16 + q * 4 + s][n * 16 + cr] =
                  fmaf(-2.f, acc[m][n][s], sqj);
          }
        }
      }
      __syncthreads();
      if (tid < BI) {  // 2 waves scan; (r+c)%32 banks -> conflict-free
        const int r = tid;
        const int gi = i0 + r;
        const int jb = j0 + h * 64;
        float worst = topv[r][KSEL - 1];
        for (int c = 0; c < 64; ++c) {
          const float v = keys[r][c];
          const int j = jb + c;
          if (v < worst && j != gi) {
            int p = KSEL - 1;
            while (p > 0 && topv[r][p - 1] > v) {
              topv[r][p] = topv[r][p - 1];
              topi[r][p] = topi[r][p - 1];
              --p;
            }
            topv[r][p] = v;
            topi[r][p] = j;
            worst = topv[r][KSEL - 1];
          }
        }
      }
    }
  }

  __syncthreads();
  if (tid < BI) {
    const int gi = i0 + tid;
#pragma unroll
    for (int k = 0; k < KSEL; ++k) {
      cand_val[((size_t)gi * NCHUNK + chunk) * KSEL + k] = topv[tid][k];
      cand_idx[((size_t)gi * NCHUNK + chunk) * KSEL + k] = topi[tid][k];
    }
  }
}

// ---------------- kernel 2: merge, exact fp32 rescore, solve 10x10, loss ----------------
__global__ __launch_bounds__(64) void lle_loss_kernel(
    const float* __restrict__ X, const float* __restrict__ Z,
    const float* __restrict__ sq, const float* __restrict__ cand_val,
    const int* __restrict__ cand_idx, float* __restrict__ out) {
  const int i = blockIdx.x;
  const int lane = threadIdx.x;
  __shared__ float av[NCHUNK * KSEL];
  __shared__ int ai[NCHUNK * KSEL];
  __shared__ int cidx[KSEL];
  __shared__ float cval[KSEL];
  __shared__ int nbr[KNN];
  __shared__ float Cm[KNN][KNN];
  __shared__ float ysh[KNN];
  __shared__ float wsh[KNN];

  av[lane] = cand_val[(size_t)i * (NCHUNK * KSEL) + lane];
  av[lane + 64] = cand_val[(size_t)i * (NCHUNK * KSEL) + lane + 64];
  ai[lane] = cand_idx[(size_t)i * (NCHUNK * KSEL) + lane];
  ai[lane + 64] = cand_idx[(size_t)i * (NCHUNK * KSEL) + lane + 64];
  __syncthreads();

  if (lane == 0) {  // merge 8 chunk lists by approx key -> approx top-16
    float bv[KSEL];
    int bx[KSEL];
#pragma unroll
    for (int k = 0; k < KSEL; ++k) { bv[k] = FLT_MAX; bx[k] = -1; }
    for (int c = 0; c < NCHUNK * KSEL; ++c) {
      const float v = av[c];
      const int id = ai[c];
      if (v < bv[KSEL - 1]) {
        int p = KSEL - 1;
        while (p > 0 && bv[p - 1] > v) {
          bv[p] = bv[p - 1];
          bx[p] = bx[p - 1];
          --p;
        }
        bv[p] = v;
        bx[p] = id;
      }
    }
#pragma unroll
    for (int k = 0; k < KSEL; ++k) cidx[k] = bx[k];
  }
  __syncthreads();

  float xi[8];
  {
    const float4 v0 = *(const float4*)&X[(size_t)i * D + lane * 8];
    const float4 v1 = *(const float4*)&X[(size_t)i * D + lane * 8 + 4];
    xi[0] = v0.x; xi[1] = v0.y; xi[2] = v0.z; xi[3] = v0.w;
    xi[4] = v1.x; xi[5] = v1.y; xi[6] = v1.z; xi[7] = v1.w;
  }

  // exact fp32 rescore of the 16 candidates
  for (int k = 0; k < KSEL; ++k) {
    const int j = cidx[k];
    const float4 u0 = *(const float4*)&X[(size_t)j * D + lane * 8];
    const float4 u1 = *(const float4*)&X[(size_t)j * D + lane * 8 + 4];
    float p = 0.f;
    p = fmaf(xi[0], u0.x, p); p = fmaf(xi[1], u0.y, p);
    p = fmaf(xi[2], u0.z, p); p = fmaf(xi[3], u0.w, p);
    p = fmaf(xi[4], u1.x, p); p = fmaf(xi[5], u1.y, p);
    p = fmaf(xi[6], u1.z, p); p = fmaf(xi[7], u1.w, p);
#pragma unroll
    for (int off = 32; off; off >>= 1) p += __shfl_xor(p, off);
    if (lane == 0) cval[k] = sq[j] - 2.f * p;
  }
  __syncthreads();

  if (lane == 0) {  // exact top-10 of the 16
    float bv[KNN];
    int bx[KNN];
#pragma unroll
    for (int k = 0; k < KNN; ++k) { bv[k] = FLT_MAX; bx[k] = -1; }
    for (int c = 0; c < KSEL; ++c) {
      const float v = cval[c];
      if (v < bv[KNN - 1]) {
        int p = KNN - 1;
        while (p > 0 && bv[p - 1] > v) {
          bv[p] = bv[p - 1];
          bx[p] = bx[p - 1];
          --p;
        }
        bv[p] = v;
        bx[p] = cidx[c];
      }
    }
#pragma unroll
    for (int k = 0; k < KNN; ++k) nbr[k] = bx[k];
  }
  __syncthreads();

  // diffs in registers (lane owns 8 contiguous dims)
  float df[KNN][8];
#pragma unroll
  for (int k = 0; k < KNN; ++k) {
    const int j = nbr[k];
    const float4 u0 = *(const float4*)&X[(size_t)j * D + lane * 8];
    const float4 u1 = *(const float4*)&X[(size_t)j * D + lane * 8 + 4];
    df[k][0] = u0.x - xi[0]; df[k][1] = u0.y - xi[1];
    df[k][2] = u0.z - xi[2]; df[k][3] = u0.w - xi[3];
    df[k][4] = u1.x - xi[4]; df[k][5] = u1.y - xi[5];
    df[k][6] = u1.z - xi[6]; df[k][7] = u1.w - xi[7];
  }

  // Gram matrix via wave reductions
#pragma unroll
  for (int k = 0; k < KNN; ++k) {
#pragma unroll
    for (int l = k; l < KNN; ++l) {
      float p = 0.f;
#pragma unroll
      for (int c = 0; c < 8; ++c) p = fmaf(df[k][c], df[l][c], p);
#pragma unroll
      for (int off = 32; off; off >>= 1) p += __shfl_xor(p, off);
      if (lane == 0) {
        Cm[k][l] = p;
        Cm[l][k] = p;
      }
    }
  }

  if (lane == 0) {  // Cholesky solve in LDS
    for (int j = 0; j < KNN; ++j) Cm[j][j] += REGC;
    for (int j = 0; j < KNN; ++j) {
      float s = Cm[j][j];
      for (int t = 0; t < j; ++t) s -= Cm[j][t] * Cm[j][t];
      const float Ljj = sqrtf(s);
      Cm[j][j] = Ljj;
      const float inv = 1.f / Ljj;
      for (int r = j + 1; r < KNN; ++r) {
        float s2 = Cm[r][j];
        for (int t = 0; t < j; ++t) s2 -= Cm[r][t] * Cm[j][t];
        Cm[r][j] = s2 * inv;
      }
    }
    for (int r = 0; r < KNN; ++r) {  // L y = 1
      float s = 1.f;
      for (int t = 0; t < r; ++t) s -= Cm[r][t] * ysh[t];
      ysh[r] = s / Cm[r][r];
    }
    for (int r = KNN - 1; r >= 0; --r) {  // L^T w = y
      float s2 = ysh[r];
      for (int t = r + 1; t < KNN; ++t) s2 -= Cm[t][r] * wsh[t];
      wsh[r] = s2 / Cm[r][r];
    }
    float s = 0.f;
    for (int k = 0; k < KNN; ++k) s += wsh[k];
    const float invs = 1.f / s;
    for (int k = 0; k < KNN; ++k) wsh[k] *= invs;
  }
  __syncthreads();

  // lane == output dim (DZ == 64)
  float zr = 0.f;
#pragma unroll
  for (int k = 0; k < KNN; ++k)
    zr = fmaf(wsh[k], Z[(size_t)nbr[k] * DZ + lane], zr);
  const float e = zr - Z[(size_t)i * DZ + lane];
  float se = e * e;
#pragma unroll
  for (int off = 32; off; off >>= 1) se += __shfl_xor(se, off);
  if (lane == 0) atomicAdd(out, se * (1.f / ((float)N * DZ)));
}

// ---------------- launch ----------------
extern "C" void kernel_launch(void* const* d_in, const int* in_sizes, int n_in,
                              void* d_out, int out_size, void* d_ws, size_t ws_size,
                              hipStream_t stream) {
  const float* X = (const float*)d_in[0];
  const float* Z = (const float*)d_in[1];
  float* out = (float*)d_out;

  char* ws = (char*)d_ws;
  float* sq = (float*)ws;                                    // 32 KB
  ushort* Xb = (ushort*)(ws + 64 * 1024);                    // 8 MB
  float* cand_val = (float*)(ws + 64 * 1024 + (size_t)N * D * 2);  // 4 MB
  int* cand_idx = (int*)(ws + 64 * 1024 + (size_t)N * D * 2 +
                         (size_t)N * NCHUNK * KSEL * 4);     // 4 MB

  hipMemsetAsync(d_out, 0, sizeof(float), stream);
  prep_kernel<<<N, 64, 0, stream>>>(X, sq, Xb);
  knn_kernel<<<dim3(N / BI, NCHUNK), 256, 0, stream>>>(Xb, sq, cand_val, cand_idx);
  lle_loss_kernel<<<N, 64, 0, stream>>>(X, Z, sq, cand_val, cand_idx, out);
}

// Round 3
// 328.602 us; speedup vs baseline: 5.1573x; 3.6623x over previous
//
#include <hip/hip_runtime.h>
#include <hip/hip_bf16.h>
#include <float.h>

#define N 8192
#define D 512
#define DZ 64
#define KNN 10
#define KSEL 16
#define REGC 1e-6f

#define BI 128
#define BJ 128
#define BK 32
#define NCHUNK 8
#define JCHUNK (N / NCHUNK)  // 1024
#define NJT (JCHUNK / BJ)    // 8

typedef __attribute__((ext_vector_type(8))) short short8v;  // 8 bf16
typedef __attribute__((ext_vector_type(4))) float f32x4;    // MFMA acc
typedef __attribute__((ext_vector_type(4))) int int4v;      // 16B move

// ---------------- kernel 0: sq (fp32) + bf16 copy of X ----------------
__global__ __launch_bounds__(64) void prep_kernel(const float* __restrict__ X,
                                                  float* __restrict__ sq,
                                                  ushort* __restrict__ Xb) {
  const int i = blockIdx.x;
  const int lane = threadIdx.x;
  const float4 v0 = *(const float4*)&X[(size_t)i * D + lane * 8];
  const float4 v1 = *(const float4*)&X[(size_t)i * D + lane * 8 + 4];
  float vv[8] = {v0.x, v0.y, v0.z, v0.w, v1.x, v1.y, v1.z, v1.w};
  ushort h[8];
  float s = 0.f;
#pragma unroll
  for (int j = 0; j < 8; ++j) {
    s = fmaf(vv[j], vv[j], s);
    __hip_bfloat16 b = __float2bfloat16(vv[j]);
    h[j] = *(ushort*)&b;
  }
  *(int4v*)&Xb[(size_t)i * D + lane * 8] = *(int4v*)h;
#pragma unroll
  for (int off = 32; off; off >>= 1) s += __shfl_xor(s, off);
  if (lane == 0) sq[i] = s;
}

// ---------------- kernel 1: bf16 MFMA distance GEMM + branchless reg top-16 ----------------
// key(i,j) = sq[j] - 2*dot_bf16(x_i,x_j), packed to sortable u32 (19b key | 13b idx).
// Each of 256 threads owns (row = tid>>1, col-half = tid&1) and keeps top-16 in VGPRs.
__global__ __launch_bounds__(256) void knn_kernel(const ushort* __restrict__ Xb,
                                                  const float* __restrict__ sq,
                                                  uint* __restrict__ cand) {
  __shared__ ushort As[BI][BK];   // 8 KB, 16B-group XOR-swizzled by (row>>1)&3
  __shared__ ushort Bs[BJ][BK];   // 8 KB
  __shared__ float keys[BI][65];  // 33.3 KB; stride 65 -> scan reads 2-way (free)

  const int i0 = blockIdx.x * BI;
  const int chunk = blockIdx.y;
  const int tid = threadIdx.x;
  const int lane = tid & 63;
  const int wave = tid >> 6;
  const int wr = wave >> 1;
  const int wc = wave & 1;

  // staging: thread -> (srow, 16B group), dest group XOR-swizzled
  const int srow = tid >> 2;
  const int sg = tid & 3;
  const int ssrc = sg * 8;
  const int sdst = (sg ^ ((srow >> 1) & 3)) * 8;  // same swz for row srow and 64+srow

  // fragment read: swizzle reduces to lane constant ((cr>>1)&3)
  const int q = lane >> 4;
  const int cr = lane & 15;
  const int fcol = (q ^ ((cr >> 1) & 3)) * 8;

  // scan: thread -> (row r, col half ch)
  const int r = tid >> 1;
  const int ch = tid & 1;
  const int gi = i0 + r;

  uint top[KSEL];
#pragma unroll
  for (int k = 0; k < KSEL; ++k) top[k] = 0xFFFFFFFFu;

#pragma unroll 1
  for (int jt = 0; jt < NJT; ++jt) {
    const int j0 = chunk * JCHUNK + jt * BJ;
    f32x4 acc[4][4];
#pragma unroll
    for (int m = 0; m < 4; ++m)
#pragma unroll
      for (int n = 0; n < 4; ++n) acc[m][n] = (f32x4){0.f, 0.f, 0.f, 0.f};

#pragma unroll 1
    for (int kt = 0; kt < D / BK; ++kt) {
      const int k0 = kt * BK;
      const int4v a0 = *(const int4v*)&Xb[(size_t)(i0 + srow) * D + k0 + ssrc];
      const int4v a1 = *(const int4v*)&Xb[(size_t)(i0 + 64 + srow) * D + k0 + ssrc];
      const int4v b0 = *(const int4v*)&Xb[(size_t)(j0 + srow) * D + k0 + ssrc];
      const int4v b1 = *(const int4v*)&Xb[(size_t)(j0 + 64 + srow) * D + k0 + ssrc];
      __syncthreads();  // prior As/Bs frag reads done
      *(int4v*)&As[srow][sdst] = a0;
      *(int4v*)&As[64 + srow][sdst] = a1;
      *(int4v*)&Bs[srow][sdst] = b0;
      *(int4v*)&Bs[64 + srow][sdst] = b1;
      __syncthreads();

      short8v a[4], b[4];
#pragma unroll
      for (int m = 0; m < 4; ++m)
        a[m] = *(const short8v*)&As[wr * 64 + m * 16 + cr][fcol];
#pragma unroll
      for (int n = 0; n < 4; ++n)
        b[n] = *(const short8v*)&Bs[wc * 64 + n * 16 + cr][fcol];
#pragma unroll
      for (int m = 0; m < 4; ++m)
#pragma unroll
        for (int n = 0; n < 4; ++n)
          acc[m][n] = __builtin_amdgcn_mfma_f32_16x16x32_bf16(a[m], b[n], acc[m][n], 0, 0, 0);
    }

#pragma unroll 1
    for (int h = 0; h < 2; ++h) {
      __syncthreads();  // prior scan reads of keys done
      if (wc == h) {
        // C/D layout: col = cr, row = q*4 + s  [m89-verified]
#pragma unroll
        for (int n = 0; n < 4; ++n) {
          const float sqj = sq[j0 + h * 64 + n * 16 + cr];
#pragma unroll
          for (int m = 0; m < 4; ++m) {
#pragma unroll
            for (int s = 0; s < 4; ++s)
              keys[wr * 64 + m * 16 + q * 4 + s][n * 16 + cr] =
                  fmaf(-2.f, acc[m][n][s], sqj);
          }
        }
      }
      __syncthreads();
      // branchless register top-16: 32 candidates per thread, no LDS lists
      const int jb = j0 + h * 64 + ch * 32;
#pragma unroll
      for (int c = 0; c < 32; ++c) {
        const float f = keys[r][ch * 32 + c];
        uint u = __float_as_uint(f);
        u ^= (uint)((int)u >> 31) | 0x80000000u;  // monotone float->uint
        uint pk = (u & 0xFFFFE000u) | (uint)(jb + c);
        pk = (jb + c == gi) ? 0xFFFFFFFFu : pk;  // exclude diagonal
#pragma unroll
        for (int kk = 0; kk < KSEL; ++kk) {  // sorted-insert via compare-exchange
          const uint lo = pk < top[kk] ? pk : top[kk];
          const uint hi = pk < top[kk] ? top[kk] : pk;
          top[kk] = lo;
          pk = hi;
        }
      }
    }
  }

  // merge the two col-half lists per row; output 16 packed candidates
  __syncthreads();
  uint* stg = (uint*)&keys[0][0];  // reuse: 128*17 u32 = 8.7 KB
  if (ch == 1) {
#pragma unroll
    for (int k = 0; k < KSEL; ++k) stg[r * 17 + k] = top[k];
  }
  __syncthreads();
  if (ch == 0) {
#pragma unroll
    for (int k = 0; k < KSEL; ++k) {
      uint pk = stg[r * 17 + k];
#pragma unroll
      for (int kk = 0; kk < KSEL; ++kk) {
        const uint lo = pk < top[kk] ? pk : top[kk];
        const uint hi = pk < top[kk] ? top[kk] : pk;
        top[kk] = lo;
        pk = hi;
      }
    }
#pragma unroll
    for (int k = 0; k < KSEL; ++k)
      cand[((size_t)gi * NCHUNK + chunk) * KSEL + k] = top[k];
  }
}

// ---------------- kernel 2: wave-parallel merge, exact rescore, solve, loss ----------------
__global__ __launch_bounds__(64) void lle_loss_kernel(
    const float* __restrict__ X, const float* __restrict__ Z,
    const float* __restrict__ sq, const uint* __restrict__ cand,
    float* __restrict__ out) {
  const int i = blockIdx.x;
  const int lane = threadIdx.x;
  __shared__ int cidx[KSEL];
  __shared__ float cval[KSEL];
  __shared__ int nbr[KNN];
  __shared__ float Cm[KNN][KNN];
  __shared__ float ysh[KNN];
  __shared__ float wsh[KNN];

  // 128 packed candidates (8 chunks x 16), globally unique values
  uint p0 = cand[(size_t)i * (NCHUNK * KSEL) + lane];
  uint p1 = cand[(size_t)i * (NCHUNK * KSEL) + 64 + lane];
#pragma unroll 1
  for (int k = 0; k < KSEL; ++k) {  // 16x wave-argmin
    const uint m = p0 < p1 ? p0 : p1;
    uint mn = m;
#pragma unroll
    for (int off = 1; off < 64; off <<= 1) {
      const uint o = __shfl_xor(mn, off);
      mn = o < mn ? o : mn;
    }
    if (lane == 0) cidx[k] = (int)(mn & 0x1FFFu);
    if (m == mn) {  // exactly one lane owns the min
      if (p0 == mn) p0 = 0xFFFFFFFFu; else p1 = 0xFFFFFFFFu;
    }
  }
  __syncthreads();

  float xi[8];
  {
    const float4 v0 = *(const float4*)&X[(size_t)i * D + lane * 8];
    const float4 v1 = *(const float4*)&X[(size_t)i * D + lane * 8 + 4];
    xi[0] = v0.x; xi[1] = v0.y; xi[2] = v0.z; xi[3] = v0.w;
    xi[4] = v1.x; xi[5] = v1.y; xi[6] = v1.z; xi[7] = v1.w;
  }

  // exact fp32 rescore of the 16 candidates
#pragma unroll 1
  for (int k = 0; k < KSEL; ++k) {
    const int j = cidx[k];
    const float4 u0 = *(const float4*)&X[(size_t)j * D + lane * 8];
    const float4 u1 = *(const float4*)&X[(size_t)j * D + lane * 8 + 4];
    float p = 0.f;
    p = fmaf(xi[0], u0.x, p); p = fmaf(xi[1], u0.y, p);
    p = fmaf(xi[2], u0.z, p); p = fmaf(xi[3], u0.w, p);
    p = fmaf(xi[4], u1.x, p); p = fmaf(xi[5], u1.y, p);
    p = fmaf(xi[6], u1.z, p); p = fmaf(xi[7], u1.w, p);
#pragma unroll
    for (int off = 32; off; off >>= 1) p += __shfl_xor(p, off);
    if (lane == 0) cval[k] = sq[j] - 2.f * p;
  }
  __syncthreads();

  if (lane == 0) {  // exact top-10 of 16
    float bv[KNN];
    int bx[KNN];
#pragma unroll
    for (int k = 0; k < KNN; ++k) { bv[k] = FLT_MAX; bx[k] = -1; }
    for (int c = 0; c < KSEL; ++c) {
      const float v = cval[c];
      if (v < bv[KNN - 1]) {
        int p = KNN - 1;
        while (p > 0 && bv[p - 1] > v) {
          bv[p] = bv[p - 1];
          bx[p] = bx[p - 1];
          --p;
        }
        bv[p] = v;
        bx[p] = cidx[c];
      }
    }
#pragma unroll
    for (int k = 0; k < KNN; ++k) nbr[k] = bx[k];
  }
  __syncthreads();

  // diffs in registers (lane owns 8 contiguous dims)
  float df[KNN][8];
#pragma unroll
  for (int k = 0; k < KNN; ++k) {
    const int j = nbr[k];
    const float4 u0 = *(const float4*)&X[(size_t)j * D + lane * 8];
    const float4 u1 = *(const float4*)&X[(size_t)j * D + lane * 8 + 4];
    df[k][0] = u0.x - xi[0]; df[k][1] = u0.y - xi[1];
    df[k][2] = u0.z - xi[2]; df[k][3] = u0.w - xi[3];
    df[k][4] = u1.x - xi[4]; df[k][5] = u1.y - xi[5];
    df[k][6] = u1.z - xi[6]; df[k][7] = u1.w - xi[7];
  }

  // Gram matrix via wave reductions
#pragma unroll
  for (int k = 0; k < KNN; ++k) {
#pragma unroll
    for (int l = k; l < KNN; ++l) {
      float p = 0.f;
#pragma unroll
      for (int c = 0; c < 8; ++c) p = fmaf(df[k][c], df[l][c], p);
#pragma unroll
      for (int off = 32; off; off >>= 1) p += __shfl_xor(p, off);
      if (lane == 0) {
        Cm[k][l] = p;
        Cm[l][k] = p;
      }
    }
  }

  if (lane == 0) {  // Cholesky solve in LDS
    for (int j = 0; j < KNN; ++j) Cm[j][j] += REGC;
    for (int j = 0; j < KNN; ++j) {
      float s = Cm[j][j];
      for (int t = 0; t < j; ++t) s -= Cm[j][t] * Cm[j][t];
      const float Ljj = sqrtf(s);
      Cm[j][j] = Ljj;
      const float inv = 1.f / Ljj;
      for (int r2 = j + 1; r2 < KNN; ++r2) {
        float s2 = Cm[r2][j];
        for (int t = 0; t < j; ++t) s2 -= Cm[r2][t] * Cm[j][t];
        Cm[r2][j] = s2 * inv;
      }
    }
    for (int r2 = 0; r2 < KNN; ++r2) {  // L y = 1
      float s = 1.f;
      for (int t = 0; t < r2; ++t) s -= Cm[r2][t] * ysh[t];
      ysh[r2] = s / Cm[r2][r2];
    }
    for (int r2 = KNN - 1; r2 >= 0; --r2) {  // L^T w = y
      float s2 = ysh[r2];
      for (int t = r2 + 1; t < KNN; ++t) s2 -= Cm[t][r2] * wsh[t];
      wsh[r2] = s2 / Cm[r2][r2];
    }
    float s = 0.f;
    for (int k = 0; k < KNN; ++k) s += wsh[k];
    const float invs = 1.f / s;
    for (int k = 0; k < KNN; ++k) wsh[k] *= invs;
  }
  __syncthreads();

  // lane == output dim (DZ == 64)
  float zr = 0.f;
#pragma unroll
  for (int k = 0; k < KNN; ++k)
    zr = fmaf(wsh[k], Z[(size_t)nbr[k] * DZ + lane], zr);
  const float e = zr - Z[(size_t)i * DZ + lane];
  float se = e * e;
#pragma unroll
  for (int off = 32; off; off >>= 1) se += __shfl_xor(se, off);
  if (lane == 0) atomicAdd(out, se * (1.f / ((float)N * DZ)));
}

// ---------------- launch ----------------
extern "C" void kernel_launch(void* const* d_in, const int* in_sizes, int n_in,
                              void* d_out, int out_size, void* d_ws, size_t ws_size,
                              hipStream_t stream) {
  const float* X = (const float*)d_in[0];
  const float* Z = (const float*)d_in[1];
  float* out = (float*)d_out;

  char* ws = (char*)d_ws;
  float* sq = (float*)ws;                                  // 32 KB (pad to 64)
  ushort* Xb = (ushort*)(ws + 64 * 1024);                  // 8 MB
  uint* cand = (uint*)(ws + 64 * 1024 + (size_t)N * D * 2);  // 4 MB

  hipMemsetAsync(d_out, 0, sizeof(float), stream);
  prep_kernel<<<N, 64, 0, stream>>>(X, sq, Xb);
  knn_kernel<<<dim3(N / BI, NCHUNK), 256, 0, stream>>>(Xb, sq, cand);
  lle_loss_kernel<<<N, 64, 0, stream>>>(X, Z, sq, cand, out);
}

// Round 4
// 275.048 us; speedup vs baseline: 6.1615x; 1.1947x over previous
//
#include <hip/hip_runtime.h>
#include <hip/hip_bf16.h>
#include <float.h>
#include <stdint.h>

#define N 8192
#define D 512
#define DZ 64
#define KNN 10
#define KSEL 16
#define REGC 1e-6f
#define KEYBIAS 4096.0f

#define BI 128
#define BJ 128
#define BK 32
#define NCHUNK 8
#define JCHUNK (N / NCHUNK)  // 1024
#define NJT (JCHUNK / BJ)    // 8
#define NKT (D / BK)         // 16
#define NT (NJT * NKT)       // 128

typedef __attribute__((ext_vector_type(8))) short short8v;
typedef __attribute__((ext_vector_type(4))) float f32x4;
typedef __attribute__((ext_vector_type(4))) int int4v;
typedef __attribute__((ext_vector_type(4))) uint uint4v;

#define WAITV0 asm volatile("s_waitcnt vmcnt(0)" ::: "memory")
#define WAITL0 asm volatile("s_waitcnt lgkmcnt(0)" ::: "memory")
#define BAR __builtin_amdgcn_s_barrier()

__device__ __forceinline__ void gld16(const ushort* g, ushort* l) {
  __builtin_amdgcn_global_load_lds(
      (const __attribute__((address_space(1))) uint32_t*)g,
      (__attribute__((address_space(3))) uint32_t*)l, 16, 0, 0);
}

// branchless sorted-insert into ascending 4-list (7 min/max)
#define INS4(L, xv)                                                  \
  do {                                                               \
    uint _x = (xv);                                                  \
    uint _l0 = _x < L[0] ? _x : L[0];                                \
    uint _h0 = _x < L[0] ? L[0] : _x;                                \
    L[0] = _l0;                                                      \
    uint _l1 = _h0 < L[1] ? _h0 : L[1];                              \
    uint _h1 = _h0 < L[1] ? L[1] : _h0;                              \
    L[1] = _l1;                                                      \
    uint _l2 = _h1 < L[2] ? _h1 : L[2];                              \
    uint _h2 = _h1 < L[2] ? L[2] : _h1;                              \
    L[2] = _l2;                                                      \
    L[3] = _h2 < L[3] ? _h2 : L[3];                                  \
  } while (0)

// ---------------- kernel 0: sq, sqb = sq + bias, bf16 copy ----------------
__global__ __launch_bounds__(64) void prep_kernel(const float* __restrict__ X,
                                                  float* __restrict__ sq,
                                                  float* __restrict__ sqb,
                                                  ushort* __restrict__ Xb) {
  const int i = blockIdx.x;
  const int lane = threadIdx.x;
  const float4 v0 = *(const float4*)&X[(size_t)i * D + lane * 8];
  const float4 v1 = *(const float4*)&X[(size_t)i * D + lane * 8 + 4];
  float vv[8] = {v0.x, v0.y, v0.z, v0.w, v1.x, v1.y, v1.z, v1.w};
  ushort h[8];
  float s = 0.f;
#pragma unroll
  for (int j = 0; j < 8; ++j) {
    s = fmaf(vv[j], vv[j], s);
    __hip_bfloat16 b = __float2bfloat16(vv[j]);
    h[j] = *(ushort*)&b;
  }
  *(int4v*)&Xb[(size_t)i * D + lane * 8] = *(int4v*)h;
#pragma unroll
  for (int off = 32; off; off >>= 1) s += __shfl_xor(s, off);
  if (lane == 0) {
    sq[i] = s;
    sqb[i] = s + KEYBIAS;
  }
}

// ---------------- kernel 1: MFMA GEMM + packed-u32 top-4x2 selection ----------------
// key(i,j) = (sq[j]+4096) - 2*dot_bf16(x_i,x_j) > 0  -> IEEE bits sort directly.
// packed = (bits & ~0x3FF) | (j - chunk*1024)  (10-bit local idx, quantum <= 0.5)
__global__ __launch_bounds__(256) void knn_kernel(const ushort* __restrict__ Xb,
                                                  const float* __restrict__ sqb,
                                                  uint* __restrict__ cand) {
  __shared__ ushort As[2][BI][BK];  // 16 KB (double-buffered)
  __shared__ ushort Bs[2][BJ][BK];  // 16 KB
  __shared__ uint keys[BI][64];     // 32 KB, one 64-col half at a time

  const int i0 = blockIdx.x * BI;
  const int chunk = blockIdx.y;
  const int jbase = chunk * JCHUNK;
  const int tid = threadIdx.x;
  const int lane = tid & 63;
  const int wave = tid >> 6;
  const int wr = wave >> 1, wc = wave & 1;
  const int q = lane >> 4, cr = lane & 15;

  // staging: thread -> 16B; LDS dest is linear (tid*16), source col pre-swizzled
  const int srow = tid >> 2, sg = tid & 3;
  const int scsw = (sg ^ ((srow >> 1) & 3)) * 8;  // same for srow and srow+64
  const size_t aoff0 = (size_t)(i0 + srow) * D + scsw;
  const size_t aoff1 = (size_t)(i0 + 64 + srow) * D + scsw;
  const size_t boff0 = (size_t)(jbase + srow) * D + scsw;

  // fragment read col (swizzle reduces to lane constant)
  const int fcol = (q ^ ((cr >> 1) & 3)) * 8;

  // keys write offsets, jt-invariant: row=wr*64+m*16+q*4+s, col group swizzled
  uint offns[4][4];
#pragma unroll
  for (int n = 0; n < 4; ++n)
#pragma unroll
    for (int s = 0; s < 4; ++s)
      offns[n][s] = (uint)((wr * 64 + q * 4 + s) * 256 +
                           (((n * 4 + (cr >> 2)) ^ (q * 4 + s)) << 4) +
                           (cr & 3) * 4);

  // scan: thread (r, ch), 8 b128 reads of 4 cands each per half
  const int r = tid >> 1, ch = tid & 1;
  uint sca[8];
#pragma unroll
  for (int cc = 0; cc < 8; ++cc)
    sca[cc] = (uint)(r * 256 + ((((ch << 3) | cc) ^ (r & 15)) << 4));

  uint LA[4], LB[4];
#pragma unroll
  for (int k = 0; k < 4; ++k) {
    LA[k] = 0xFFFFFFFFu;
    LB[k] = 0xFFFFFFFFu;
  }

  auto STAGE = [&](int tt) {
    const int jt_ = tt >> 4;
    const int bf = tt & 1;
    const int ko = (tt & 15) * BK;
    gld16(Xb + aoff0 + ko, &As[bf][srow][sg * 8]);
    gld16(Xb + aoff1 + ko, &As[bf][64 + srow][sg * 8]);
    const size_t bo = boff0 + (size_t)jt_ * (BJ * D) + ko;
    gld16(Xb + bo, &Bs[bf][srow][sg * 8]);
    gld16(Xb + bo + (size_t)64 * D, &Bs[bf][64 + srow][sg * 8]);
  };

  f32x4 acc[4][4];
#pragma unroll
  for (int m = 0; m < 4; ++m)
#pragma unroll
    for (int n = 0; n < 4; ++n) acc[m][n] = (f32x4){0.f, 0.f, 0.f, 0.f};

  STAGE(0);

#pragma unroll 1
  for (int t = 0; t < NT; ++t) {
    const int jt = t >> 4;
    const int buf = t & 1;
    WAITV0;  // my 4 loads for this K-step landed
    BAR;     // everyone's landed; everyone's prior frag reads done
    STAGE((t + 1) & (NT - 1));  // next K-step flies under the MFMAs (t=127: harmless dummy)

    const ushort(*Ab)[BK] = As[buf];
    const ushort(*Bb)[BK] = Bs[buf];
    short8v a[4], b[4];
#pragma unroll
    for (int m = 0; m < 4; ++m)
      a[m] = *(const short8v*)&Ab[wr * 64 + m * 16 + cr][fcol];
#pragma unroll
    for (int n = 0; n < 4; ++n)
      b[n] = *(const short8v*)&Bb[wc * 64 + n * 16 + cr][fcol];
#pragma unroll
    for (int m = 0; m < 4; ++m)
#pragma unroll
      for (int n = 0; n < 4; ++n)
        acc[m][n] = __builtin_amdgcn_mfma_f32_16x16x32_bf16(a[m], b[n], acc[m][n], 0, 0, 0);

    if ((t & 15) == 15) {  // end of jt: keys + selection, two 64-col halves
#pragma unroll
      for (int h = 0; h < 2; ++h) {
        if (h == 1) BAR;  // h0 scan values consumed before h1 overwrites
        if (wc == h) {
#pragma unroll
          for (int n = 0; n < 4; ++n) {
            const float sqjb = sqb[jbase + jt * BJ + h * 64 + n * 16 + cr];
            const uint idxn = (uint)(jt * 128 + h * 64 + n * 16 + cr);
#pragma unroll
            for (int m = 0; m < 4; ++m)
#pragma unroll
              for (int s = 0; s < 4; ++s) {
                const float f = fmaf(-2.f, acc[m][n][s], sqjb);  // > 0 by bias
                const uint pk = (__float_as_uint(f) & 0xFFFFFC00u) | idxn;
                *(uint*)((char*)keys + offns[n][s] + m * 4096) = pk;
              }
          }
        }
        WAITL0;
        BAR;
        if (jt < 4) {
#pragma unroll
          for (int cc = 0; cc < 8; ++cc) {
            const uint4v v = *(const uint4v*)((const char*)keys + sca[cc]);
            INS4(LA, v[0]);
            INS4(LA, v[1]);
            INS4(LA, v[2]);
            INS4(LA, v[3]);
          }
        } else {
#pragma unroll
          for (int cc = 0; cc < 8; ++cc) {
            const uint4v v = *(const uint4v*)((const char*)keys + sca[cc]);
            INS4(LB, v[0]);
            INS4(LB, v[1]);
            INS4(LB, v[2]);
            INS4(LB, v[3]);
          }
        }
      }
#pragma unroll
      for (int m = 0; m < 4; ++m)
#pragma unroll
        for (int n = 0; n < 4; ++n) acc[m][n] = (f32x4){0.f, 0.f, 0.f, 0.f};
    }
  }

  uint* dst = &cand[((size_t)(i0 + r) * NCHUNK + chunk) * KSEL + ch * 8];
#pragma unroll
  for (int k = 0; k < 4; ++k) {
    dst[k] = LA[k];
    dst[4 + k] = LB[k];
  }
}

// ---------------- kernel 2: u64 merge, exact rescore, solve 10x10, loss ----------------
__global__ __launch_bounds__(64) void lle_loss_kernel(
    const float* __restrict__ X, const float* __restrict__ Z,
    const float* __restrict__ sq, const uint* __restrict__ cand,
    float* __restrict__ out) {
  const int i = blockIdx.x;
  const int lane = threadIdx.x;
  __shared__ int cidx[KSEL];
  __shared__ float cval[KSEL];
  __shared__ int nbr[KNN];
  __shared__ float Cm[KNN][KNN];
  __shared__ float ysh[KNN];
  __shared__ float wsh[KNN];

  // 128 entries (8 chunks x 16); decode to globally-ordered unique u64 (key22, gidx13)
  const uint pk0 = cand[(size_t)i * 128 + lane];
  const uint pk1 = cand[(size_t)i * 128 + 64 + lane];
  const int g0 = (lane >> 4) * 1024 + (int)(pk0 & 0x3FFu);
  const int g1 = ((64 + lane) >> 4) * 1024 + (int)(pk1 & 0x3FFu);
  unsigned long long k0 =
      ((unsigned long long)(pk0 >> 10) << 13) | (unsigned long long)g0;
  unsigned long long k1 =
      ((unsigned long long)(pk1 >> 10) << 13) | (unsigned long long)g1;
  if (g0 == i) k0 = ~0ull;  // self-exclusion (diagonal is rank-1 in its stream)
  if (g1 == i) k1 = ~0ull;

#pragma unroll 1
  for (int k = 0; k < KSEL; ++k) {
    unsigned long long mn = k0 < k1 ? k0 : k1;
#pragma unroll
    for (int off = 32; off; off >>= 1) {
      const unsigned long long o = __shfl_xor(mn, off);
      mn = o < mn ? o : mn;
    }
    if (k0 == mn) {  // values unique -> exactly one lane, one slot
      cidx[k] = (int)(mn & 0x1FFFull);
      k0 = ~0ull;
    } else if (k1 == mn) {
      cidx[k] = (int)(mn & 0x1FFFull);
      k1 = ~0ull;
    }
  }
  __syncthreads();

  float xi[8];
  {
    const float4 v0 = *(const float4*)&X[(size_t)i * D + lane * 8];
    const float4 v1 = *(const float4*)&X[(size_t)i * D + lane * 8 + 4];
    xi[0] = v0.x; xi[1] = v0.y; xi[2] = v0.z; xi[3] = v0.w;
    xi[4] = v1.x; xi[5] = v1.y; xi[6] = v1.z; xi[7] = v1.w;
  }

  // exact fp32 rescore of the 16 candidates (unrolled: loads batch, latency hides)
#pragma unroll 4
  for (int k = 0; k < KSEL; ++k) {
    const int j = cidx[k];
    const float4 u0 = *(const float4*)&X[(size_t)j * D + lane * 8];
    const float4 u1 = *(const float4*)&X[(size_t)j * D + lane * 8 + 4];
    float p = 0.f;
    p = fmaf(xi[0], u0.x, p); p = fmaf(xi[1], u0.y, p);
    p = fmaf(xi[2], u0.z, p); p = fmaf(xi[3], u0.w, p);
    p = fmaf(xi[4], u1.x, p); p = fmaf(xi[5], u1.y, p);
    p = fmaf(xi[6], u1.z, p); p = fmaf(xi[7], u1.w, p);
#pragma unroll
    for (int off = 32; off; off >>= 1) p += __shfl_xor(p, off);
    if (lane == 0) cval[k] = sq[j] - 2.f * p;
  }
  __syncthreads();

  if (lane == 0) {  // exact top-10 of 16
    float bv[KNN];
    int bx[KNN];
#pragma unroll
    for (int k = 0; k < KNN; ++k) { bv[k] = FLT_MAX; bx[k] = -1; }
    for (int c = 0; c < KSEL; ++c) {
      const float v = cval[c];
      if (v < bv[KNN - 1]) {
        int p = KNN - 1;
        while (p > 0 && bv[p - 1] > v) {
          bv[p] = bv[p - 1];
          bx[p] = bx[p - 1];
          --p;
        }
        bv[p] = v;
        bx[p] = cidx[c];
      }
    }
#pragma unroll
    for (int k = 0; k < KNN; ++k) nbr[k] = bx[k];
  }
  __syncthreads();

  // diffs in registers (lane owns 8 contiguous dims)
  float df[KNN][8];
#pragma unroll
  for (int k = 0; k < KNN; ++k) {
    const int j = nbr[k];
    const float4 u0 = *(const float4*)&X[(size_t)j * D + lane * 8];
    const float4 u1 = *(const float4*)&X[(size_t)j * D + lane * 8 + 4];
    df[k][0] = u0.x - xi[0]; df[k][1] = u0.y - xi[1];
    df[k][2] = u0.z - xi[2]; df[k][3] = u0.w - xi[3];
    df[k][4] = u1.x - xi[4]; df[k][5] = u1.y - xi[5];
    df[k][6] = u1.z - xi[6]; df[k][7] = u1.w - xi[7];
  }

  // Gram matrix via wave reductions
#pragma unroll
  for (int k = 0; k < KNN; ++k) {
#pragma unroll
    for (int l = k; l < KNN; ++l) {
      float p = 0.f;
#pragma unroll
      for (int c = 0; c < 8; ++c) p = fmaf(df[k][c], df[l][c], p);
#pragma unroll
      for (int off = 32; off; off >>= 1) p += __shfl_xor(p, off);
      if (lane == 0) {
        Cm[k][l] = p;
        Cm[l][k] = p;
      }
    }
  }

  if (lane == 0) {  // Cholesky solve in LDS
    for (int j = 0; j < KNN; ++j) Cm[j][j] += REGC;
    for (int j = 0; j < KNN; ++j) {
      float s = Cm[j][j];
      for (int t = 0; t < j; ++t) s -= Cm[j][t] * Cm[j][t];
      const float Ljj = sqrtf(s);
      Cm[j][j] = Ljj;
      const float inv = 1.f / Ljj;
      for (int r2 = j + 1; r2 < KNN; ++r2) {
        float s2 = Cm[r2][j];
        for (int t = 0; t < j; ++t) s2 -= Cm[r2][t] * Cm[j][t];
        Cm[r2][j] = s2 * inv;
      }
    }
    for (int r2 = 0; r2 < KNN; ++r2) {  // L y = 1
      float s = 1.f;
      for (int t = 0; t < r2; ++t) s -= Cm[r2][t] * ysh[t];
      ysh[r2] = s / Cm[r2][r2];
    }
    for (int r2 = KNN - 1; r2 >= 0; --r2) {  // L^T w = y
      float s2 = ysh[r2];
      for (int t = r2 + 1; t < KNN; ++t) s2 -= Cm[t][r2] * wsh[t];
      wsh[r2] = s2 / Cm[r2][r2];
    }
    float s = 0.f;
    for (int k = 0; k < KNN; ++k) s += wsh[k];
    const float invs = 1.f / s;
    for (int k = 0; k < KNN; ++k) wsh[k] *= invs;
  }
  __syncthreads();

  // lane == output dim (DZ == 64)
  float zr = 0.f;
#pragma unroll
  for (int k = 0; k < KNN; ++k)
    zr = fmaf(wsh[k], Z[(size_t)nbr[k] * DZ + lane], zr);
  const float e = zr - Z[(size_t)i * DZ + lane];
  float se = e * e;
#pragma unroll
  for (int off = 32; off; off >>= 1) se += __shfl_xor(se, off);
  if (lane == 0) atomicAdd(out, se * (1.f / ((float)N * DZ)));
}

// ---------------- launch ----------------
extern "C" void kernel_launch(void* const* d_in, const int* in_sizes, int n_in,
                              void* d_out, int out_size, void* d_ws, size_t ws_size,
                              hipStream_t stream) {
  const float* X = (const float*)d_in[0];
  const float* Z = (const float*)d_in[1];
  float* out = (float*)d_out;

  char* ws = (char*)d_ws;
  float* sq = (float*)ws;                                   // 32 KB
  float* sqb = (float*)(ws + 32 * 1024);                    // 32 KB
  ushort* Xb = (ushort*)(ws + 64 * 1024);                   // 8 MB
  uint* cand = (uint*)(ws + 64 * 1024 + (size_t)N * D * 2); // 4 MB

  hipMemsetAsync(d_out, 0, sizeof(float), stream);
  prep_kernel<<<N, 64, 0, stream>>>(X, sq, sqb, Xb);
  knn_kernel<<<dim3(N / BI, NCHUNK), 256, 0, stream>>>(Xb, sqb, cand);
  lle_loss_kernel<<<N, 64, 0, stream>>>(X, Z, sq, cand, out);
}

// Round 5
// 260.980 us; speedup vs baseline: 6.4936x; 1.0539x over previous
//
#include <hip/hip_runtime.h>
#include <hip/hip_bf16.h>
#include <float.h>
#include <stdint.h>

#define N 8192
#define D 512
#define DZ 64
#define KNN 10
#define KSEL 16
#define REGC 1e-6f
#define KEYBIAS 4096.0f

#define BI 128
#define BJ 128
#define BK 32
#define NCHUNK 8
#define JCHUNK (N / NCHUNK)  // 1024
#define NJT (JCHUNK / BJ)    // 8
#define NKT (D / BK)         // 16
#define NT (NJT * NKT)       // 128

typedef __attribute__((ext_vector_type(8))) short short8v;
typedef __attribute__((ext_vector_type(4))) float f32x4;
typedef __attribute__((ext_vector_type(4))) int int4v;
typedef __attribute__((ext_vector_type(4))) uint uint4v;

#define WAITV0 asm volatile("s_waitcnt vmcnt(0)" ::: "memory")
#define WAITL0 asm volatile("s_waitcnt lgkmcnt(0)" ::: "memory")
#define BAR __builtin_amdgcn_s_barrier()

__device__ __forceinline__ void gld16(const ushort* g, ushort* l) {
  __builtin_amdgcn_global_load_lds(
      (const __attribute__((address_space(1))) uint32_t*)g,
      (__attribute__((address_space(3))) uint32_t*)l, 16, 0, 0);
}

// branchless sorted-insert into ascending 4-list (7 min/max)
#define INS4(L, xv)                                                  \
  do {                                                               \
    uint _x = (xv);                                                  \
    uint _l0 = _x < L[0] ? _x : L[0];                                \
    uint _h0 = _x < L[0] ? L[0] : _x;                                \
    L[0] = _l0;                                                      \
    uint _l1 = _h0 < L[1] ? _h0 : L[1];                              \
    uint _h1 = _h0 < L[1] ? L[1] : _h0;                              \
    L[1] = _l1;                                                      \
    uint _l2 = _h1 < L[2] ? _h1 : L[2];                              \
    uint _h2 = _h1 < L[2] ? L[2] : _h1;                              \
    L[2] = _l2;                                                      \
    L[3] = _h2 < L[3] ? _h2 : L[3];                                  \
  } while (0)

// ---------------- kernel 0: sq, sqb = sq + bias, bf16 copy ----------------
__global__ __launch_bounds__(64) void prep_kernel(const float* __restrict__ X,
                                                  float* __restrict__ sq,
                                                  float* __restrict__ sqb,
                                                  ushort* __restrict__ Xb) {
  const int i = blockIdx.x;
  const int lane = threadIdx.x;
  const float4 v0 = *(const float4*)&X[(size_t)i * D + lane * 8];
  const float4 v1 = *(const float4*)&X[(size_t)i * D + lane * 8 + 4];
  float vv[8] = {v0.x, v0.y, v0.z, v0.w, v1.x, v1.y, v1.z, v1.w};
  ushort h[8];
  float s = 0.f;
#pragma unroll
  for (int j = 0; j < 8; ++j) {
    s = fmaf(vv[j], vv[j], s);
    __hip_bfloat16 b = __float2bfloat16(vv[j]);
    h[j] = *(ushort*)&b;
  }
  *(int4v*)&Xb[(size_t)i * D + lane * 8] = *(int4v*)h;
#pragma unroll
  for (int off = 32; off; off >>= 1) s += __shfl_xor(s, off);
  if (lane == 0) {
    sq[i] = s;
    sqb[i] = s + KEYBIAS;
  }
}

// ---------------- kernel 1: MFMA GEMM + packed-u32 top-4x2 selection ----------------
// (unchanged from round 4)
__global__ __launch_bounds__(256) void knn_kernel(const ushort* __restrict__ Xb,
                                                  const float* __restrict__ sqb,
                                                  uint* __restrict__ cand) {
  __shared__ ushort As[2][BI][BK];
  __shared__ ushort Bs[2][BJ][BK];
  __shared__ uint keys[BI][64];

  const int i0 = blockIdx.x * BI;
  const int chunk = blockIdx.y;
  const int jbase = chunk * JCHUNK;
  const int tid = threadIdx.x;
  const int lane = tid & 63;
  const int wave = tid >> 6;
  const int wr = wave >> 1, wc = wave & 1;
  const int q = lane >> 4, cr = lane & 15;

  const int srow = tid >> 2, sg = tid & 3;
  const int scsw = (sg ^ ((srow >> 1) & 3)) * 8;
  const size_t aoff0 = (size_t)(i0 + srow) * D + scsw;
  const size_t aoff1 = (size_t)(i0 + 64 + srow) * D + scsw;
  const size_t boff0 = (size_t)(jbase + srow) * D + scsw;

  const int fcol = (q ^ ((cr >> 1) & 3)) * 8;

  uint offns[4][4];
#pragma unroll
  for (int n = 0; n < 4; ++n)
#pragma unroll
    for (int s = 0; s < 4; ++s)
      offns[n][s] = (uint)((wr * 64 + q * 4 + s) * 256 +
                           (((n * 4 + (cr >> 2)) ^ (q * 4 + s)) << 4) +
                           (cr & 3) * 4);

  const int r = tid >> 1, ch = tid & 1;
  uint sca[8];
#pragma unroll
  for (int cc = 0; cc < 8; ++cc)
    sca[cc] = (uint)(r * 256 + ((((ch << 3) | cc) ^ (r & 15)) << 4));

  uint LA[4], LB[4];
#pragma unroll
  for (int k = 0; k < 4; ++k) {
    LA[k] = 0xFFFFFFFFu;
    LB[k] = 0xFFFFFFFFu;
  }

  auto STAGE = [&](int tt) {
    const int jt_ = tt >> 4;
    const int bf = tt & 1;
    const int ko = (tt & 15) * BK;
    gld16(Xb + aoff0 + ko, &As[bf][srow][sg * 8]);
    gld16(Xb + aoff1 + ko, &As[bf][64 + srow][sg * 8]);
    const size_t bo = boff0 + (size_t)jt_ * (BJ * D) + ko;
    gld16(Xb + bo, &Bs[bf][srow][sg * 8]);
    gld16(Xb + bo + (size_t)64 * D, &Bs[bf][64 + srow][sg * 8]);
  };

  f32x4 acc[4][4];
#pragma unroll
  for (int m = 0; m < 4; ++m)
#pragma unroll
    for (int n = 0; n < 4; ++n) acc[m][n] = (f32x4){0.f, 0.f, 0.f, 0.f};

  STAGE(0);

#pragma unroll 1
  for (int t = 0; t < NT; ++t) {
    const int jt = t >> 4;
    const int buf = t & 1;
    WAITV0;
    BAR;
    STAGE((t + 1) & (NT - 1));

    const ushort(*Ab)[BK] = As[buf];
    const ushort(*Bb)[BK] = Bs[buf];
    short8v a[4], b[4];
#pragma unroll
    for (int m = 0; m < 4; ++m)
      a[m] = *(const short8v*)&Ab[wr * 64 + m * 16 + cr][fcol];
#pragma unroll
    for (int n = 0; n < 4; ++n)
      b[n] = *(const short8v*)&Bb[wc * 64 + n * 16 + cr][fcol];
#pragma unroll
    for (int m = 0; m < 4; ++m)
#pragma unroll
      for (int n = 0; n < 4; ++n)
        acc[m][n] = __builtin_amdgcn_mfma_f32_16x16x32_bf16(a[m], b[n], acc[m][n], 0, 0, 0);

    if ((t & 15) == 15) {
#pragma unroll
      for (int h = 0; h < 2; ++h) {
        if (h == 1) BAR;
        if (wc == h) {
#pragma unroll
          for (int n = 0; n < 4; ++n) {
            const float sqjb = sqb[jbase + jt * BJ + h * 64 + n * 16 + cr];
            const uint idxn = (uint)(jt * 128 + h * 64 + n * 16 + cr);
#pragma unroll
            for (int m = 0; m < 4; ++m)
#pragma unroll
              for (int s = 0; s < 4; ++s) {
                const float f = fmaf(-2.f, acc[m][n][s], sqjb);
                const uint pk = (__float_as_uint(f) & 0xFFFFFC00u) | idxn;
                *(uint*)((char*)keys + offns[n][s] + m * 4096) = pk;
              }
          }
        }
        WAITL0;
        BAR;
        if (jt < 4) {
#pragma unroll
          for (int cc = 0; cc < 8; ++cc) {
            const uint4v v = *(const uint4v*)((const char*)keys + sca[cc]);
            INS4(LA, v[0]);
            INS4(LA, v[1]);
            INS4(LA, v[2]);
            INS4(LA, v[3]);
          }
        } else {
#pragma unroll
          for (int cc = 0; cc < 8; ++cc) {
            const uint4v v = *(const uint4v*)((const char*)keys + sca[cc]);
            INS4(LB, v[0]);
            INS4(LB, v[1]);
            INS4(LB, v[2]);
            INS4(LB, v[3]);
          }
        }
      }
#pragma unroll
      for (int m = 0; m < 4; ++m)
#pragma unroll
        for (int n = 0; n < 4; ++n) acc[m][n] = (f32x4){0.f, 0.f, 0.f, 0.f};
    }
  }

  uint* dst = &cand[((size_t)(i0 + r) * NCHUNK + chunk) * KSEL + ch * 8];
#pragma unroll
  for (int k = 0; k < 4; ++k) {
    dst[k] = LA[k];
    dst[4 + k] = LB[k];
  }
}

// ---------------- kernel 2: LDS-free all-lane merge/rescore/solve/loss ----------------
__global__ __launch_bounds__(64) void lle_loss_kernel(
    const float* __restrict__ X, const float* __restrict__ Z,
    const float* __restrict__ sqb, const uint* __restrict__ cand,
    float* __restrict__ out) {
  const int i = blockIdx.x;
  const int lane = threadIdx.x;

  // 128 entries (8 chunks x 16) -> unique u64 (approx key 22b || gidx 13b)
  const uint pk0 = cand[(size_t)i * 128 + lane];
  const uint pk1 = cand[(size_t)i * 128 + 64 + lane];
  const int g0 = (lane >> 4) * 1024 + (int)(pk0 & 0x3FFu);
  const int g1 = ((64 + lane) >> 4) * 1024 + (int)(pk1 & 0x3FFu);
  unsigned long long k0 =
      ((unsigned long long)(pk0 >> 10) << 13) | (unsigned long long)g0;
  unsigned long long k1 =
      ((unsigned long long)(pk1 >> 10) << 13) | (unsigned long long)g1;
  if (g0 == i) k0 = ~0ull;  // self-exclusion
  if (g1 == i) k1 = ~0ull;

  // approx top-16 via 16x butterfly argmin; every lane keeps all results
  int cidx[KSEL];
#pragma unroll
  for (int k = 0; k < KSEL; ++k) {
    unsigned long long mn = k0 < k1 ? k0 : k1;
#pragma unroll
    for (int off = 32; off; off >>= 1) {
      const unsigned long long o = __shfl_xor(mn, off);
      mn = o < mn ? o : mn;
    }
    cidx[k] = (int)(mn & 0x1FFFull);
    const bool e0 = (k0 == mn);
    const bool e1 = (!e0) && (k1 == mn);
    k0 = e0 ? ~0ull : k0;
    k1 = e1 ? ~0ull : k1;
  }

  float xi[8];
  {
    const float4 v0 = *(const float4*)&X[(size_t)i * D + lane * 8];
    const float4 v1 = *(const float4*)&X[(size_t)i * D + lane * 8 + 4];
    xi[0] = v0.x; xi[1] = v0.y; xi[2] = v0.z; xi[3] = v0.w;
    xi[4] = v1.x; xi[5] = v1.y; xi[6] = v1.z; xi[7] = v1.w;
  }

  // exact fp32 rescore; key = biased-positive fp32 bits (exact order) || gidx
  unsigned long long cv[KSEL];
#pragma unroll
  for (int k = 0; k < KSEL; ++k) {
    const int j = cidx[k];
    const float4 u0 = *(const float4*)&X[(size_t)j * D + lane * 8];
    const float4 u1 = *(const float4*)&X[(size_t)j * D + lane * 8 + 4];
    float p = 0.f;
    p = fmaf(xi[0], u0.x, p); p = fmaf(xi[1], u0.y, p);
    p = fmaf(xi[2], u0.z, p); p = fmaf(xi[3], u0.w, p);
    p = fmaf(xi[4], u1.x, p); p = fmaf(xi[5], u1.y, p);
    p = fmaf(xi[6], u1.z, p); p = fmaf(xi[7], u1.w, p);
#pragma unroll
    for (int off = 32; off; off >>= 1) p += __shfl_xor(p, off);
    const float f = fmaf(-2.f, p, sqb[j]);  // > 0, all lanes hold it
    cv[k] = ((unsigned long long)__float_as_uint(f) << 32) | (unsigned long long)(uint)j;
  }

  // exact top-10 of 16 via compare-exchange network (all lanes, registers)
  unsigned long long T[KNN];
#pragma unroll
  for (int k = 0; k < KNN; ++k) T[k] = ~0ull;
#pragma unroll
  for (int c = 0; c < KSEL; ++c) {
    unsigned long long x = cv[c];
#pragma unroll
    for (int qq = 0; qq < KNN; ++qq) {
      const unsigned long long lo = x < T[qq] ? x : T[qq];
      const unsigned long long hi = x < T[qq] ? T[qq] : x;
      T[qq] = lo;
      x = hi;
    }
  }
  int nbrj[KNN];
#pragma unroll
  for (int k = 0; k < KNN; ++k) nbrj[k] = (int)(T[k] & 0x1FFFull);

  // diffs in registers (lane owns 8 contiguous dims)
  float df[KNN][8];
#pragma unroll
  for (int k = 0; k < KNN; ++k) {
    const int j = nbrj[k];
    const float4 u0 = *(const float4*)&X[(size_t)j * D + lane * 8];
    const float4 u1 = *(const float4*)&X[(size_t)j * D + lane * 8 + 4];
    df[k][0] = u0.x - xi[0]; df[k][1] = u0.y - xi[1];
    df[k][2] = u0.z - xi[2]; df[k][3] = u0.w - xi[3];
    df[k][4] = u1.x - xi[4]; df[k][5] = u1.y - xi[5];
    df[k][6] = u1.z - xi[6]; df[k][7] = u1.w - xi[7];
  }

  // Gram lower triangle via butterfly reductions -> every lane has C
  float C[KNN][KNN];
#pragma unroll
  for (int k = 0; k < KNN; ++k) {
#pragma unroll
    for (int l = 0; l <= k; ++l) {
      float p = 0.f;
#pragma unroll
      for (int c = 0; c < 8; ++c) p = fmaf(df[k][c], df[l][c], p);
#pragma unroll
      for (int off = 32; off; off >>= 1) p += __shfl_xor(p, off);
      C[k][l] = p;
    }
  }

  // all-lane static-register Cholesky + solve (zero LDS, zero divergence)
  float dinv[KNN];
#pragma unroll
  for (int j = 0; j < KNN; ++j) {
    float s = C[j][j] + REGC;
#pragma unroll
    for (int t = 0; t < KNN; ++t)
      if (t < j) s -= C[j][t] * C[j][t];
    const float dj = sqrtf(s);
    const float inv = 1.f / dj;
    dinv[j] = inv;
#pragma unroll
    for (int r2 = 0; r2 < KNN; ++r2) {
      if (r2 > j) {
        float s2 = C[r2][j];
#pragma unroll
        for (int t = 0; t < KNN; ++t)
          if (t < j) s2 -= C[r2][t] * C[j][t];
        C[r2][j] = s2 * inv;
      }
    }
  }
  float y[KNN], w[KNN];
#pragma unroll
  for (int r2 = 0; r2 < KNN; ++r2) {  // L y = 1
    float s = 1.f;
#pragma unroll
    for (int t = 0; t < KNN; ++t)
      if (t < r2) s -= C[r2][t] * y[t];
    y[r2] = s * dinv[r2];
  }
#pragma unroll
  for (int r2 = KNN - 1; r2 >= 0; --r2) {  // L^T w = y
    float s2 = y[r2];
#pragma unroll
    for (int t = 0; t < KNN; ++t)
      if (t > r2) s2 -= C[t][r2] * w[t];
    w[r2] = s2 * dinv[r2];
  }
  float ws = 0.f;
#pragma unroll
  for (int k = 0; k < KNN; ++k) ws += w[k];
  const float winv = 1.f / ws;

  // reconstruction (lane == output dim, DZ == 64)
  float zr = 0.f;
#pragma unroll
  for (int k = 0; k < KNN; ++k)
    zr = fmaf(w[k] * winv, Z[(size_t)nbrj[k] * DZ + lane], zr);
  const float e = zr - Z[(size_t)i * DZ + lane];
  float se = e * e;
#pragma unroll
  for (int off = 32; off; off >>= 1) se += __shfl_xor(se, off);
  if (lane == 0) atomicAdd(out, se * (1.f / ((float)N * DZ)));
}

// ---------------- launch ----------------
extern "C" void kernel_launch(void* const* d_in, const int* in_sizes, int n_in,
                              void* d_out, int out_size, void* d_ws, size_t ws_size,
                              hipStream_t stream) {
  const float* X = (const float*)d_in[0];
  const float* Z = (const float*)d_in[1];
  float* out = (float*)d_out;

  char* ws = (char*)d_ws;
  float* sq = (float*)ws;                                   // 32 KB
  float* sqb = (float*)(ws + 32 * 1024);                    // 32 KB
  ushort* Xb = (ushort*)(ws + 64 * 1024);                   // 8 MB
  uint* cand = (uint*)(ws + 64 * 1024 + (size_t)N * D * 2); // 4 MB

  hipMemsetAsync(d_out, 0, sizeof(float), stream);
  prep_kernel<<<N, 64, 0, stream>>>(X, sq, sqb, Xb);
  knn_kernel<<<dim3(N / BI, NCHUNK), 256, 0, stream>>>(Xb, sqb, cand);
  lle_loss_kernel<<<N, 64, 0, stream>>>(X, Z, sqb, cand, out);
}

// Round 6
// 189.887 us; speedup vs baseline: 8.9248x; 1.3744x over previous
//
#include <hip/hip_runtime.h>
#include <hip/hip_bf16.h>
#include <float.h>
#include <stdint.h>

#define N 8192
#define D 512
#define DZ 64
#define KNN 10
#define KSEL 16
#define REGC 1e-6f
#define KEYBIAS 4096.0f

#define BI 128
#define BJ 128
#define BK 32
#define NCHUNK 8
#define JCHUNK (N / NCHUNK)  // 1024
#define NJT (JCHUNK / BJ)    // 8
#define NKT (D / BK)         // 16
#define NT (NJT * NKT)       // 128

typedef __attribute__((ext_vector_type(8))) short short8v;
typedef __attribute__((ext_vector_type(4))) float f32x4;
typedef __attribute__((ext_vector_type(4))) int int4v;
typedef __attribute__((ext_vector_type(4))) uint uint4v;

#define WAITV0 asm volatile("s_waitcnt vmcnt(0)" ::: "memory")
#define WAITL0 asm volatile("s_waitcnt lgkmcnt(0)" ::: "memory")
#define BAR __builtin_amdgcn_s_barrier()

__device__ __forceinline__ void gld16(const ushort* g, ushort* l) {
  __builtin_amdgcn_global_load_lds(
      (const __attribute__((address_space(1))) uint32_t*)g,
      (__attribute__((address_space(3))) uint32_t*)l, 16, 0, 0);
}

// branchless sorted-insert into ascending 4-list (7 min/max)
#define INS4(L, xv)                                                  \
  do {                                                               \
    uint _x = (xv);                                                  \
    uint _l0 = _x < L[0] ? _x : L[0];                                \
    uint _h0 = _x < L[0] ? L[0] : _x;                                \
    L[0] = _l0;                                                      \
    uint _l1 = _h0 < L[1] ? _h0 : L[1];                              \
    uint _h1 = _h0 < L[1] ? L[1] : _h0;                              \
    L[1] = _l1;                                                      \
    uint _l2 = _h1 < L[2] ? _h1 : L[2];                              \
    uint _h2 = _h1 < L[2] ? L[2] : _h1;                              \
    L[2] = _l2;                                                      \
    L[3] = _h2 < L[3] ? _h2 : L[3];                                  \
  } while (0)

// ---------------- kernel 0: sq, sqb = sq + bias, bf16 copy ----------------
__global__ __launch_bounds__(64) void prep_kernel(const float* __restrict__ X,
                                                  float* __restrict__ sq,
                                                  float* __restrict__ sqb,
                                                  ushort* __restrict__ Xb) {
  const int i = blockIdx.x;
  const int lane = threadIdx.x;
  const float4 v0 = *(const float4*)&X[(size_t)i * D + lane * 8];
  const float4 v1 = *(const float4*)&X[(size_t)i * D + lane * 8 + 4];
  float vv[8] = {v0.x, v0.y, v0.z, v0.w, v1.x, v1.y, v1.z, v1.w};
  ushort h[8];
  float s = 0.f;
#pragma unroll
  for (int j = 0; j < 8; ++j) {
    s = fmaf(vv[j], vv[j], s);
    __hip_bfloat16 b = __float2bfloat16(vv[j]);
    h[j] = *(ushort*)&b;
  }
  *(int4v*)&Xb[(size_t)i * D + lane * 8] = *(int4v*)h;
#pragma unroll
  for (int off = 32; off; off >>= 1) s += __shfl_xor(s, off);
  if (lane == 0) {
    sq[i] = s;
    sqb[i] = s + KEYBIAS;
  }
}

// ---------------- kernel 1: MFMA GEMM + packed-u32 top-4x2 selection ----------------
// (unchanged from round 5)
__global__ __launch_bounds__(256) void knn_kernel(const ushort* __restrict__ Xb,
                                                  const float* __restrict__ sqb,
                                                  uint* __restrict__ cand) {
  __shared__ ushort As[2][BI][BK];
  __shared__ ushort Bs[2][BJ][BK];
  __shared__ uint keys[BI][64];

  const int i0 = blockIdx.x * BI;
  const int chunk = blockIdx.y;
  const int jbase = chunk * JCHUNK;
  const int tid = threadIdx.x;
  const int lane = tid & 63;
  const int wave = tid >> 6;
  const int wr = wave >> 1, wc = wave & 1;
  const int q = lane >> 4, cr = lane & 15;

  const int srow = tid >> 2, sg = tid & 3;
  const int scsw = (sg ^ ((srow >> 1) & 3)) * 8;
  const size_t aoff0 = (size_t)(i0 + srow) * D + scsw;
  const size_t aoff1 = (size_t)(i0 + 64 + srow) * D + scsw;
  const size_t boff0 = (size_t)(jbase + srow) * D + scsw;

  const int fcol = (q ^ ((cr >> 1) & 3)) * 8;

  uint offns[4][4];
#pragma unroll
  for (int n = 0; n < 4; ++n)
#pragma unroll
    for (int s = 0; s < 4; ++s)
      offns[n][s] = (uint)((wr * 64 + q * 4 + s) * 256 +
                           (((n * 4 + (cr >> 2)) ^ (q * 4 + s)) << 4) +
                           (cr & 3) * 4);

  const int r = tid >> 1, ch = tid & 1;
  uint sca[8];
#pragma unroll
  for (int cc = 0; cc < 8; ++cc)
    sca[cc] = (uint)(r * 256 + ((((ch << 3) | cc) ^ (r & 15)) << 4));

  uint LA[4], LB[4];
#pragma unroll
  for (int k = 0; k < 4; ++k) {
    LA[k] = 0xFFFFFFFFu;
    LB[k] = 0xFFFFFFFFu;
  }

  auto STAGE = [&](int tt) {
    const int jt_ = tt >> 4;
    const int bf = tt & 1;
    const int ko = (tt & 15) * BK;
    gld16(Xb + aoff0 + ko, &As[bf][srow][sg * 8]);
    gld16(Xb + aoff1 + ko, &As[bf][64 + srow][sg * 8]);
    const size_t bo = boff0 + (size_t)jt_ * (BJ * D) + ko;
    gld16(Xb + bo, &Bs[bf][srow][sg * 8]);
    gld16(Xb + bo + (size_t)64 * D, &Bs[bf][64 + srow][sg * 8]);
  };

  f32x4 acc[4][4];
#pragma unroll
  for (int m = 0; m < 4; ++m)
#pragma unroll
    for (int n = 0; n < 4; ++n) acc[m][n] = (f32x4){0.f, 0.f, 0.f, 0.f};

  STAGE(0);

#pragma unroll 1
  for (int t = 0; t < NT; ++t) {
    const int jt = t >> 4;
    const int buf = t & 1;
    WAITV0;
    BAR;
    STAGE((t + 1) & (NT - 1));

    const ushort(*Ab)[BK] = As[buf];
    const ushort(*Bb)[BK] = Bs[buf];
    short8v a[4], b[4];
#pragma unroll
    for (int m = 0; m < 4; ++m)
      a[m] = *(const short8v*)&Ab[wr * 64 + m * 16 + cr][fcol];
#pragma unroll
    for (int n = 0; n < 4; ++n)
      b[n] = *(const short8v*)&Bb[wc * 64 + n * 16 + cr][fcol];
#pragma unroll
    for (int m = 0; m < 4; ++m)
#pragma unroll
      for (int n = 0; n < 4; ++n)
        acc[m][n] = __builtin_amdgcn_mfma_f32_16x16x32_bf16(a[m], b[n], acc[m][n], 0, 0, 0);

    if ((t & 15) == 15) {
#pragma unroll
      for (int h = 0; h < 2; ++h) {
        if (h == 1) BAR;
        if (wc == h) {
#pragma unroll
          for (int n = 0; n < 4; ++n) {
            const float sqjb = sqb[jbase + jt * BJ + h * 64 + n * 16 + cr];
            const uint idxn = (uint)(jt * 128 + h * 64 + n * 16 + cr);
#pragma unroll
            for (int m = 0; m < 4; ++m)
#pragma unroll
              for (int s = 0; s < 4; ++s) {
                const float f = fmaf(-2.f, acc[m][n][s], sqjb);
                const uint pk = (__float_as_uint(f) & 0xFFFFFC00u) | idxn;
                *(uint*)((char*)keys + offns[n][s] + m * 4096) = pk;
              }
          }
        }
        WAITL0;
        BAR;
        if (jt < 4) {
#pragma unroll
          for (int cc = 0; cc < 8; ++cc) {
            const uint4v v = *(const uint4v*)((const char*)keys + sca[cc]);
            INS4(LA, v[0]);
            INS4(LA, v[1]);
            INS4(LA, v[2]);
            INS4(LA, v[3]);
          }
        } else {
#pragma unroll
          for (int cc = 0; cc < 8; ++cc) {
            const uint4v v = *(const uint4v*)((const char*)keys + sca[cc]);
            INS4(LB, v[0]);
            INS4(LB, v[1]);
            INS4(LB, v[2]);
            INS4(LB, v[3]);
          }
        }
      }
#pragma unroll
      for (int m = 0; m < 4; ++m)
#pragma unroll
        for (int n = 0; n < 4; ++n) acc[m][n] = (f32x4){0.f, 0.f, 0.f, 0.f};
    }
  }

  uint* dst = &cand[((size_t)(i0 + r) * NCHUNK + chunk) * KSEL + ch * 8];
#pragma unroll
  for (int k = 0; k < 4; ++k) {
    dst[k] = LA[k];
    dst[4 + k] = LB[k];
  }
}

// ---------------- kernel 2: LDS-free merge/rescore/solve; plain store of row SSE ----------------
__global__ __launch_bounds__(64) void lle_loss_kernel(
    const float* __restrict__ X, const float* __restrict__ Z,
    const float* __restrict__ sqb, const uint* __restrict__ cand,
    float* __restrict__ rowsse) {
  const int i = blockIdx.x;
  const int lane = threadIdx.x;

  // 128 entries (8 chunks x 16) -> unique u64 (approx key 22b || gidx 13b)
  const uint pk0 = cand[(size_t)i * 128 + lane];
  const uint pk1 = cand[(size_t)i * 128 + 64 + lane];
  const int g0 = (lane >> 4) * 1024 + (int)(pk0 & 0x3FFu);
  const int g1 = ((64 + lane) >> 4) * 1024 + (int)(pk1 & 0x3FFu);
  unsigned long long k0 =
      ((unsigned long long)(pk0 >> 10) << 13) | (unsigned long long)g0;
  unsigned long long k1 =
      ((unsigned long long)(pk1 >> 10) << 13) | (unsigned long long)g1;
  if (g0 == i) k0 = ~0ull;  // self-exclusion
  if (g1 == i) k1 = ~0ull;

  // approx top-16 via 16x butterfly argmin; every lane keeps all results
  int cidx[KSEL];
#pragma unroll
  for (int k = 0; k < KSEL; ++k) {
    unsigned long long mn = k0 < k1 ? k0 : k1;
#pragma unroll
    for (int off = 32; off; off >>= 1) {
      const unsigned long long o = __shfl_xor(mn, off);
      mn = o < mn ? o : mn;
    }
    cidx[k] = (int)(mn & 0x1FFFull);
    const bool e0 = (k0 == mn);
    const bool e1 = (!e0) && (k1 == mn);
    k0 = e0 ? ~0ull : k0;
    k1 = e1 ? ~0ull : k1;
  }

  float xi[8];
  {
    const float4 v0 = *(const float4*)&X[(size_t)i * D + lane * 8];
    const float4 v1 = *(const float4*)&X[(size_t)i * D + lane * 8 + 4];
    xi[0] = v0.x; xi[1] = v0.y; xi[2] = v0.z; xi[3] = v0.w;
    xi[4] = v1.x; xi[5] = v1.y; xi[6] = v1.z; xi[7] = v1.w;
  }

  // exact fp32 rescore; key = biased-positive fp32 bits (exact order) || gidx
  unsigned long long cv[KSEL];
#pragma unroll
  for (int k = 0; k < KSEL; ++k) {
    const int j = cidx[k];
    const float4 u0 = *(const float4*)&X[(size_t)j * D + lane * 8];
    const float4 u1 = *(const float4*)&X[(size_t)j * D + lane * 8 + 4];
    float p = 0.f;
    p = fmaf(xi[0], u0.x, p); p = fmaf(xi[1], u0.y, p);
    p = fmaf(xi[2], u0.z, p); p = fmaf(xi[3], u0.w, p);
    p = fmaf(xi[4], u1.x, p); p = fmaf(xi[5], u1.y, p);
    p = fmaf(xi[6], u1.z, p); p = fmaf(xi[7], u1.w, p);
#pragma unroll
    for (int off = 32; off; off >>= 1) p += __shfl_xor(p, off);
    const float f = fmaf(-2.f, p, sqb[j]);  // > 0, all lanes hold it
    cv[k] = ((unsigned long long)__float_as_uint(f) << 32) | (unsigned long long)(uint)j;
  }

  // exact top-10 of 16 via compare-exchange network (all lanes, registers)
  unsigned long long T[KNN];
#pragma unroll
  for (int k = 0; k < KNN; ++k) T[k] = ~0ull;
#pragma unroll
  for (int c = 0; c < KSEL; ++c) {
    unsigned long long x = cv[c];
#pragma unroll
    for (int qq = 0; qq < KNN; ++qq) {
      const unsigned long long lo = x < T[qq] ? x : T[qq];
      const unsigned long long hi = x < T[qq] ? T[qq] : x;
      T[qq] = lo;
      x = hi;
    }
  }
  int nbrj[KNN];
#pragma unroll
  for (int k = 0; k < KNN; ++k) nbrj[k] = (int)(T[k] & 0x1FFFull);

  // diffs in registers (lane owns 8 contiguous dims)
  float df[KNN][8];
#pragma unroll
  for (int k = 0; k < KNN; ++k) {
    const int j = nbrj[k];
    const float4 u0 = *(const float4*)&X[(size_t)j * D + lane * 8];
    const float4 u1 = *(const float4*)&X[(size_t)j * D + lane * 8 + 4];
    df[k][0] = u0.x - xi[0]; df[k][1] = u0.y - xi[1];
    df[k][2] = u0.z - xi[2]; df[k][3] = u0.w - xi[3];
    df[k][4] = u1.x - xi[4]; df[k][5] = u1.y - xi[5];
    df[k][6] = u1.z - xi[6]; df[k][7] = u1.w - xi[7];
  }

  // Gram lower triangle via butterfly reductions -> every lane has C
  float C[KNN][KNN];
#pragma unroll
  for (int k = 0; k < KNN; ++k) {
#pragma unroll
    for (int l = 0; l <= k; ++l) {
      float p = 0.f;
#pragma unroll
      for (int c = 0; c < 8; ++c) p = fmaf(df[k][c], df[l][c], p);
#pragma unroll
      for (int off = 32; off; off >>= 1) p += __shfl_xor(p, off);
      C[k][l] = p;
    }
  }

  // all-lane static-register Cholesky + solve (zero LDS, zero divergence)
  float dinv[KNN];
#pragma unroll
  for (int j = 0; j < KNN; ++j) {
    float s = C[j][j] + REGC;
#pragma unroll
    for (int t = 0; t < KNN; ++t)
      if (t < j) s -= C[j][t] * C[j][t];
    const float dj = sqrtf(s);
    const float inv = 1.f / dj;
    dinv[j] = inv;
#pragma unroll
    for (int r2 = 0; r2 < KNN; ++r2) {
      if (r2 > j) {
        float s2 = C[r2][j];
#pragma unroll
        for (int t = 0; t < KNN; ++t)
          if (t < j) s2 -= C[r2][t] * C[j][t];
        C[r2][j] = s2 * inv;
      }
    }
  }
  float y[KNN], w[KNN];
#pragma unroll
  for (int r2 = 0; r2 < KNN; ++r2) {  // L y = 1
    float s = 1.f;
#pragma unroll
    for (int t = 0; t < KNN; ++t)
      if (t < r2) s -= C[r2][t] * y[t];
    y[r2] = s * dinv[r2];
  }
#pragma unroll
  for (int r2 = KNN - 1; r2 >= 0; --r2) {  // L^T w = y
    float s2 = y[r2];
#pragma unroll
    for (int t = 0; t < KNN; ++t)
      if (t > r2) s2 -= C[t][r2] * w[t];
    w[r2] = s2 * dinv[r2];
  }
  float ws = 0.f;
#pragma unroll
  for (int k = 0; k < KNN; ++k) ws += w[k];
  const float winv = 1.f / ws;

  // reconstruction (lane == output dim, DZ == 64)
  float zr = 0.f;
#pragma unroll
  for (int k = 0; k < KNN; ++k)
    zr = fmaf(w[k] * winv, Z[(size_t)nbrj[k] * DZ + lane], zr);
  const float e = zr - Z[(size_t)i * DZ + lane];
  float se = e * e;
#pragma unroll
  for (int off = 32; off; off >>= 1) se += __shfl_xor(se, off);
  if (lane == 0) rowsse[i] = se;  // plain store: no atomic contention
}

// ---------------- kernel 3: single-block final reduction ----------------
__global__ __launch_bounds__(256) void reduce_kernel(const float* __restrict__ rowsse,
                                                     float* __restrict__ out) {
  const int tid = threadIdx.x;
  float s = 0.f;
#pragma unroll
  for (int c = 0; c < N / 256; ++c) s += rowsse[c * 256 + tid];
#pragma unroll
  for (int off = 32; off; off >>= 1) s += __shfl_xor(s, off);
  __shared__ float part[4];
  if ((tid & 63) == 0) part[tid >> 6] = s;
  __syncthreads();
  if (tid == 0)
    out[0] = (part[0] + part[1] + part[2] + part[3]) * (1.f / ((float)N * DZ));
}

// ---------------- launch ----------------
extern "C" void kernel_launch(void* const* d_in, const int* in_sizes, int n_in,
                              void* d_out, int out_size, void* d_ws, size_t ws_size,
                              hipStream_t stream) {
  const float* X = (const float*)d_in[0];
  const float* Z = (const float*)d_in[1];
  float* out = (float*)d_out;

  char* ws = (char*)d_ws;
  float* sq = (float*)ws;                                    // 32 KB
  float* sqb = (float*)(ws + 32 * 1024);                     // 32 KB
  ushort* Xb = (ushort*)(ws + 64 * 1024);                    // 8 MB
  uint* cand = (uint*)(ws + 64 * 1024 + (size_t)N * D * 2);  // 4 MB
  float* rowsse = (float*)(ws + 64 * 1024 + (size_t)N * D * 2 +
                           (size_t)N * NCHUNK * KSEL * 4);   // 32 KB

  prep_kernel<<<N, 64, 0, stream>>>(X, sq, sqb, Xb);
  knn_kernel<<<dim3(N / BI, NCHUNK), 256, 0, stream>>>(Xb, sqb, cand);
  lle_loss_kernel<<<N, 64, 0, stream>>>(X, Z, sqb, cand, rowsse);
  reduce_kernel<<<1, 256, 0, stream>>>(rowsse, out);
}

// Round 7
// 169.792 us; speedup vs baseline: 9.9811x; 1.1184x over previous
//
#include <hip/hip_runtime.h>
#include <hip/hip_bf16.h>
#include <float.h>
#include <stdint.h>

#define N 8192
#define D 512
#define DZ 64
#define KNN 10
#define KSEL 16
#define REGC 1e-6f
#define KEYBIAS 4096.0f

#define BI 128
#define BJ 128
#define BK 32
#define NCHUNK 16
#define JCHUNK (N / NCHUNK)  // 512
#define NJT (JCHUNK / BJ)    // 4
#define NKT (D / BK)         // 16
#define NT (NJT * NKT)       // 64

typedef __attribute__((ext_vector_type(8))) short short8v;
typedef __attribute__((ext_vector_type(4))) float f32x4;
typedef __attribute__((ext_vector_type(4))) int int4v;
typedef __attribute__((ext_vector_type(4))) uint uint4v;

#define WAITV0 asm volatile("s_waitcnt vmcnt(0)" ::: "memory")
#define WAITL0 asm volatile("s_waitcnt lgkmcnt(0)" ::: "memory")
#define BAR __builtin_amdgcn_s_barrier()

__device__ __forceinline__ void gld16(const ushort* g, ushort* l) {
  __builtin_amdgcn_global_load_lds(
      (const __attribute__((address_space(1))) uint32_t*)g,
      (__attribute__((address_space(3))) uint32_t*)l, 16, 0, 0);
}

// branchless sorted-insert into ascending 4-list (7 min/max)
#define INS4(L, xv)                                                  \
  do {                                                               \
    uint _x = (xv);                                                  \
    uint _l0 = _x < L[0] ? _x : L[0];                                \
    uint _h0 = _x < L[0] ? L[0] : _x;                                \
    L[0] = _l0;                                                      \
    uint _l1 = _h0 < L[1] ? _h0 : L[1];                              \
    uint _h1 = _h0 < L[1] ? L[1] : _h0;                              \
    L[1] = _l1;                                                      \
    uint _l2 = _h1 < L[2] ? _h1 : L[2];                              \
    uint _h2 = _h1 < L[2] ? L[2] : _h1;                              \
    L[2] = _l2;                                                      \
    L[3] = _h2 < L[3] ? _h2 : L[3];                                  \
  } while (0)

// ---------------- kernel 0: sqb = |x|^2 + bias, bf16 copy ----------------
__global__ __launch_bounds__(64) void prep_kernel(const float* __restrict__ X,
                                                  float* __restrict__ sqb,
                                                  ushort* __restrict__ Xb) {
  const int i = blockIdx.x;
  const int lane = threadIdx.x;
  const float4 v0 = *(const float4*)&X[(size_t)i * D + lane * 8];
  const float4 v1 = *(const float4*)&X[(size_t)i * D + lane * 8 + 4];
  float vv[8] = {v0.x, v0.y, v0.z, v0.w, v1.x, v1.y, v1.z, v1.w};
  ushort h[8];
  float s = 0.f;
#pragma unroll
  for (int j = 0; j < 8; ++j) {
    s = fmaf(vv[j], vv[j], s);
    __hip_bfloat16 b = __float2bfloat16(vv[j]);
    h[j] = *(ushort*)&b;
  }
  *(int4v*)&Xb[(size_t)i * D + lane * 8] = *(int4v*)h;
#pragma unroll
  for (int off = 32; off; off >>= 1) s += __shfl_xor(s, off);
  if (lane == 0) sqb[i] = s + KEYBIAS;
}

// ---------------- kernel 1: MFMA GEMM + packed-u32 top-4 selection ----------------
// LDS = 32KB A/B dbuf + 8KB keys = 40960 -> 4 blocks/CU. grid (64,16) = 1024 blocks.
__global__ __launch_bounds__(256, 4) void knn_kernel(const ushort* __restrict__ Xb,
                                                     const float* __restrict__ sqb,
                                                     uint* __restrict__ cand) {
  __shared__ ushort As[2][BI][BK];  // 16 KB
  __shared__ ushort Bs[2][BJ][BK];  // 16 KB
  __shared__ uint keys[BI][16];     // 8 KB (one 16-col phase at a time)

  const int i0 = blockIdx.x * BI;
  const int chunk = blockIdx.y;
  const int jbase = chunk * JCHUNK;
  const int tid = threadIdx.x;
  const int lane = tid & 63;
  const int wave = tid >> 6;
  const int wr = wave >> 1, wc = wave & 1;
  const int q = lane >> 4, cr = lane & 15;

  // staging: thread -> 16B; LDS dest linear, source col pre-swizzled
  const int srow = tid >> 2, sg = tid & 3;
  const int scsw = (sg ^ ((srow >> 1) & 3)) * 8;
  const size_t aoff0 = (size_t)(i0 + srow) * D + scsw;
  const size_t aoff1 = (size_t)(i0 + 64 + srow) * D + scsw;
  const size_t boff0 = (size_t)(jbase + srow) * D + scsw;

  // fragment read col (swizzle reduces to lane constant)
  const int fcol = (q ^ ((cr >> 1) & 3)) * 8;

  // keys write byte-offsets (s-indexed; +m*1024 per m)
  uint wo[4];
#pragma unroll
  for (int s = 0; s < 4; ++s)
    wo[s] = (uint)((wr * 64 + q * 4 + s) * 64 + cr * 4);

  // scan: thread (r, ch) reads 8 cands (2 x b128) per phase
  const int r = tid >> 1, ch = tid & 1;
  const uint sca0 = (uint)(r * 64 + ch * 32);
  const uint sca1 = sca0 + 16;

  uint LA[4], LB[4];
#pragma unroll
  for (int k = 0; k < 4; ++k) {
    LA[k] = 0xFFFFFFFFu;
    LB[k] = 0xFFFFFFFFu;
  }

  auto STAGE = [&](int tt) {
    const int jt_ = tt >> 4;
    const int bf = tt & 1;
    const int ko = (tt & 15) * BK;
    gld16(Xb + aoff0 + ko, &As[bf][srow][sg * 8]);
    gld16(Xb + aoff1 + ko, &As[bf][64 + srow][sg * 8]);
    const size_t bo = boff0 + (size_t)jt_ * (BJ * D) + ko;
    gld16(Xb + bo, &Bs[bf][srow][sg * 8]);
    gld16(Xb + bo + (size_t)64 * D, &Bs[bf][64 + srow][sg * 8]);
  };

  f32x4 acc[4][4];
#pragma unroll
  for (int m = 0; m < 4; ++m)
#pragma unroll
    for (int n = 0; n < 4; ++n) acc[m][n] = (f32x4){0.f, 0.f, 0.f, 0.f};

  STAGE(0);

#pragma unroll 1
  for (int t = 0; t < NT; ++t) {
    const int jt = t >> 4;
    const int buf = t & 1;
    WAITV0;  // my 4 loads for this K-step landed
    BAR;     // everyone's landed; prior frag reads done
    STAGE((t + 1) & (NT - 1));  // next step flies under the MFMAs

    const ushort(*Ab)[BK] = As[buf];
    const ushort(*Bb)[BK] = Bs[buf];
    short8v a[4], b[4];
#pragma unroll
    for (int m = 0; m < 4; ++m)
      a[m] = *(const short8v*)&Ab[wr * 64 + m * 16 + cr][fcol];
#pragma unroll
    for (int n = 0; n < 4; ++n)
      b[n] = *(const short8v*)&Bb[wc * 64 + n * 16 + cr][fcol];
#pragma unroll
    for (int m = 0; m < 4; ++m)
#pragma unroll
      for (int n = 0; n < 4; ++n)
        acc[m][n] = __builtin_amdgcn_mfma_f32_16x16x32_bf16(a[m], b[n], acc[m][n], 0, 0, 0);

    if ((t & 15) == 15) {  // end of jt: keys + selection, 8 phases of 16 cols
#pragma unroll
      for (int p = 0; p < 8; ++p) {
        const int h = p >> 2, n = p & 3;
        BAR;  // prior phase's scan reads done before overwrite
        if (wc == h) {
          const float sqjb = sqb[jbase + jt * BJ + h * 64 + n * 16 + cr];
          const uint idxn = (uint)(jt * 128 + h * 64 + n * 16 + cr);
#pragma unroll
          for (int m = 0; m < 4; ++m)
#pragma unroll
            for (int s = 0; s < 4; ++s) {
              const float f = fmaf(-2.f, acc[m][n][s], sqjb);  // > 0 by bias
              const uint pk = (__float_as_uint(f) & 0xFFFFFC00u) | idxn;
              *(uint*)((char*)keys + wo[s] + m * 1024) = pk;
            }
        }
        WAITL0;
        BAR;
        const uint4v v0 = *(const uint4v*)((const char*)keys + sca0);
        const uint4v v1 = *(const uint4v*)((const char*)keys + sca1);
        if (jt < 2) {
          INS4(LA, v0[0]); INS4(LA, v0[1]); INS4(LA, v0[2]); INS4(LA, v0[3]);
          INS4(LA, v1[0]); INS4(LA, v1[1]); INS4(LA, v1[2]); INS4(LA, v1[3]);
        } else {
          INS4(LB, v0[0]); INS4(LB, v0[1]); INS4(LB, v0[2]); INS4(LB, v0[3]);
          INS4(LB, v1[0]); INS4(LB, v1[1]); INS4(LB, v1[2]); INS4(LB, v1[3]);
        }
      }
#pragma unroll
      for (int m = 0; m < 4; ++m)
#pragma unroll
        for (int n = 0; n < 4; ++n) acc[m][n] = (f32x4){0.f, 0.f, 0.f, 0.f};
    }
  }

  uint* dst = &cand[((size_t)(i0 + r) * NCHUNK + chunk) * KSEL + ch * 8];
#pragma unroll
  for (int k = 0; k < 4; ++k) {
    dst[k] = LA[k];
    dst[4 + k] = LB[k];
  }
}

// ---------------- kernel 2: LDS-free merge/rescore/solve; plain store of row SSE ----------------
__global__ __launch_bounds__(64) void lle_loss_kernel(
    const float* __restrict__ X, const float* __restrict__ Z,
    const float* __restrict__ sqb, const uint* __restrict__ cand,
    float* __restrict__ rowsse) {
  const int i = blockIdx.x;
  const int lane = threadIdx.x;

  // 256 entries (16 chunks x 16) -> unique u64 (approx key || gidx13)
  const uint4v pk4 = *(const uint4v*)&cand[(size_t)i * 256 + lane * 4];
  const int chk = lane >> 2;  // (lane*4+kk)>>4 for kk=0..3
  unsigned long long cvm[4];
#pragma unroll
  for (int kk = 0; kk < 4; ++kk) {
    const int g = chk * JCHUNK + (int)(pk4[kk] & 0x3FFu);
    const unsigned long long kv =
        ((unsigned long long)(pk4[kk] >> 10) << 13) | (unsigned long long)g;
    cvm[kk] = (g == i) ? ~0ull : kv;  // self-exclusion
  }

  // approx top-16 via 16x butterfly argmin; every lane keeps all results
  int cidx[KSEL];
#pragma unroll
  for (int k = 0; k < KSEL; ++k) {
    const unsigned long long m01 = cvm[0] < cvm[1] ? cvm[0] : cvm[1];
    const unsigned long long m23 = cvm[2] < cvm[3] ? cvm[2] : cvm[3];
    unsigned long long mn = m01 < m23 ? m01 : m23;
#pragma unroll
    for (int off = 32; off; off >>= 1) {
      const unsigned long long o = __shfl_xor(mn, off);
      mn = o < mn ? o : mn;
    }
    cidx[k] = (int)(mn & 0x1FFFull);
#pragma unroll
    for (int kk = 0; kk < 4; ++kk)
      cvm[kk] = (cvm[kk] == mn) ? ~0ull : cvm[kk];  // values unique
  }

  float xi[8];
  {
    const float4 v0 = *(const float4*)&X[(size_t)i * D + lane * 8];
    const float4 v1 = *(const float4*)&X[(size_t)i * D + lane * 8 + 4];
    xi[0] = v0.x; xi[1] = v0.y; xi[2] = v0.z; xi[3] = v0.w;
    xi[4] = v1.x; xi[5] = v1.y; xi[6] = v1.z; xi[7] = v1.w;
  }

  // exact fp32 rescore; key = biased-positive fp32 bits (exact order) || gidx
  unsigned long long cv[KSEL];
#pragma unroll
  for (int k = 0; k < KSEL; ++k) {
    const int j = cidx[k];
    const float4 u0 = *(const float4*)&X[(size_t)j * D + lane * 8];
    const float4 u1 = *(const float4*)&X[(size_t)j * D + lane * 8 + 4];
    float p = 0.f;
    p = fmaf(xi[0], u0.x, p); p = fmaf(xi[1], u0.y, p);
    p = fmaf(xi[2], u0.z, p); p = fmaf(xi[3], u0.w, p);
    p = fmaf(xi[4], u1.x, p); p = fmaf(xi[5], u1.y, p);
    p = fmaf(xi[6], u1.z, p); p = fmaf(xi[7], u1.w, p);
#pragma unroll
    for (int off = 32; off; off >>= 1) p += __shfl_xor(p, off);
    const float f = fmaf(-2.f, p, sqb[j]);  // > 0, all lanes hold it
    cv[k] = ((unsigned long long)__float_as_uint(f) << 32) | (unsigned long long)(uint)j;
  }

  // exact top-10 of 16 via compare-exchange network (all lanes, registers)
  unsigned long long T[KNN];
#pragma unroll
  for (int k = 0; k < KNN; ++k) T[k] = ~0ull;
#pragma unroll
  for (int c = 0; c < KSEL; ++c) {
    unsigned long long x = cv[c];
#pragma unroll
    for (int qq = 0; qq < KNN; ++qq) {
      const unsigned long long lo = x < T[qq] ? x : T[qq];
      const unsigned long long hi = x < T[qq] ? T[qq] : x;
      T[qq] = lo;
      x = hi;
    }
  }
  int nbrj[KNN];
#pragma unroll
  for (int k = 0; k < KNN; ++k) nbrj[k] = (int)(T[k] & 0x1FFFull);

  // diffs in registers (lane owns 8 contiguous dims)
  float df[KNN][8];
#pragma unroll
  for (int k = 0; k < KNN; ++k) {
    const int j = nbrj[k];
    const float4 u0 = *(const float4*)&X[(size_t)j * D + lane * 8];
    const float4 u1 = *(const float4*)&X[(size_t)j * D + lane * 8 + 4];
    df[k][0] = u0.x - xi[0]; df[k][1] = u0.y - xi[1];
    df[k][2] = u0.z - xi[2]; df[k][3] = u0.w - xi[3];
    df[k][4] = u1.x - xi[4]; df[k][5] = u1.y - xi[5];
    df[k][6] = u1.z - xi[6]; df[k][7] = u1.w - xi[7];
  }

  // Gram lower triangle via butterfly reductions -> every lane has C
  float C[KNN][KNN];
#pragma unroll
  for (int k = 0; k < KNN; ++k) {
#pragma unroll
    for (int l = 0; l <= k; ++l) {
      float p = 0.f;
#pragma unroll
      for (int c = 0; c < 8; ++c) p = fmaf(df[k][c], df[l][c], p);
#pragma unroll
      for (int off = 32; off; off >>= 1) p += __shfl_xor(p, off);
      C[k][l] = p;
    }
  }

  // all-lane static-register Cholesky + solve (zero LDS, zero divergence)
  float dinv[KNN];
#pragma unroll
  for (int j = 0; j < KNN; ++j) {
    float s = C[j][j] + REGC;
#pragma unroll
    for (int t = 0; t < KNN; ++t)
      if (t < j) s -= C[j][t] * C[j][t];
    const float dj = sqrtf(s);
    const float inv = 1.f / dj;
    dinv[j] = inv;
#pragma unroll
    for (int r2 = 0; r2 < KNN; ++r2) {
      if (r2 > j) {
        float s2 = C[r2][j];
#pragma unroll
        for (int t = 0; t < KNN; ++t)
          if (t < j) s2 -= C[r2][t] * C[j][t];
        C[r2][j] = s2 * inv;
      }
    }
  }
  float y[KNN], w[KNN];
#pragma unroll
  for (int r2 = 0; r2 < KNN; ++r2) {  // L y = 1
    float s = 1.f;
#pragma unroll
    for (int t = 0; t < KNN; ++t)
      if (t < r2) s -= C[r2][t] * y[t];
    y[r2] = s * dinv[r2];
  }
#pragma unroll
  for (int r2 = KNN - 1; r2 >= 0; --r2) {  // L^T w = y
    float s2 = y[r2];
#pragma unroll
    for (int t = 0; t < KNN; ++t)
      if (t > r2) s2 -= C[t][r2] * w[t];
    w[r2] = s2 * dinv[r2];
  }
  float ws = 0.f;
#pragma unroll
  for (int k = 0; k < KNN; ++k) ws += w[k];
  const float winv = 1.f / ws;

  // reconstruction (lane == output dim, DZ == 64)
  float zr = 0.f;
#pragma unroll
  for (int k = 0; k < KNN; ++k)
    zr = fmaf(w[k] * winv, Z[(size_t)nbrj[k] * DZ + lane], zr);
  const float e = zr - Z[(size_t)i * DZ + lane];
  float se = e * e;
#pragma unroll
  for (int off = 32; off; off >>= 1) se += __shfl_xor(se, off);
  if (lane == 0) rowsse[i] = se;  // plain store: no atomic contention
}

// ---------------- kernel 3: single-block final reduction ----------------
__global__ __launch_bounds__(256) void reduce_kernel(const float* __restrict__ rowsse,
                                                     float* __restrict__ out) {
  const int tid = threadIdx.x;
  float s = 0.f;
#pragma unroll
  for (int c = 0; c < N / 256; ++c) s += rowsse[c * 256 + tid];
#pragma unroll
  for (int off = 32; off; off >>= 1) s += __shfl_xor(s, off);
  __shared__ float part[4];
  if ((tid & 63) == 0) part[tid >> 6] = s;
  __syncthreads();
  if (tid == 0)
    out[0] = (part[0] + part[1] + part[2] + part[3]) * (1.f / ((float)N * DZ));
}

// ---------------- launch ----------------
extern "C" void kernel_launch(void* const* d_in, const int* in_sizes, int n_in,
                              void* d_out, int out_size, void* d_ws, size_t ws_size,
                              hipStream_t stream) {
  const float* X = (const float*)d_in[0];
  const float* Z = (const float*)d_in[1];
  float* out = (float*)d_out;

  char* ws = (char*)d_ws;
  float* sqb = (float*)ws;                                   // 32 KB
  float* rowsse = (float*)(ws + 32 * 1024);                  // 32 KB
  ushort* Xb = (ushort*)(ws + 64 * 1024);                    // 8 MB
  uint* cand = (uint*)(ws + 64 * 1024 + (size_t)N * D * 2);  // 8 MB

  prep_kernel<<<N, 64, 0, stream>>>(X, sqb, Xb);
  knn_kernel<<<dim3(N / BI, NCHUNK), 256, 0, stream>>>(Xb, sqb, cand);
  lle_loss_kernel<<<N, 64, 0, stream>>>(X, Z, sqb, cand, rowsse);
  reduce_kernel<<<1, 256, 0, stream>>>(rowsse, out);
}